// Round 4
// baseline (1033.415 us; speedup 1.0000x reference)
//
#include <hip/hip_runtime.h>
#include <math.h>

#define NB 4
#define TT 16
#define NNODE 1000
#define FIN 8
#define EE 8000
#define EP 9000          // E + N self loops
#define HID 64
#define HEADS 4
#define NL 5
#define GG (NB*TT)       // 64 graphs
#define ROWS (GG*NNODE)  // 64000
#define HCOL (HEADS*HID) // 256
#define KGI (NNODE*HID)  // 64000
#define GOUT 192         // 3*HID
#define GIK 128          // K-slice per gi-gemm block
#define NSPLIT 16        // split accumulation buffers for gi

// ---------------- edge prep ----------------
__global__ void k_build_edges(const int* __restrict__ eidx, int* __restrict__ src_e,
                              int* __restrict__ dst_e, int* __restrict__ deg, int* __restrict__ fill) {
    int i = blockIdx.x * blockDim.x + threadIdx.x;
    if (i < EP) {
        int s, d;
        if (i < EE) { s = eidx[i]; d = eidx[EE + i]; }
        else { s = i - EE; d = i - EE; }
        src_e[i] = s; dst_e[i] = d;
    }
    if (i < NNODE) { deg[i] = 0; fill[i] = 0; }
}

__global__ void k_csr_count(const int* __restrict__ dst_e, int* __restrict__ deg) {
    int i = blockIdx.x * blockDim.x + threadIdx.x;
    if (i < EP) atomicAdd(&deg[dst_e[i]], 1);
}

// parallel inclusive scan over 1024 (padded) in LDS
__global__ __launch_bounds__(256) void k_csr_scan(const int* __restrict__ deg, int* __restrict__ rowptr) {
    __shared__ int s[1024];
    int tid = threadIdx.x;
    for (int i = tid; i < 1024; i += 256) s[i] = (i < NNODE) ? deg[i] : 0;
    __syncthreads();
    for (int off = 1; off < 1024; off <<= 1) {
        int t[4];
        #pragma unroll
        for (int q = 0; q < 4; q++) { int i = tid + 256 * q; t[q] = (i >= off) ? s[i - off] : 0; }
        __syncthreads();
        #pragma unroll
        for (int q = 0; q < 4; q++) { int i = tid + 256 * q; s[i] += t[q]; }
        __syncthreads();
    }
    for (int i = tid; i < NNODE; i += 256) rowptr[i + 1] = s[i];
    if (tid == 0) rowptr[0] = 0;
}

__global__ void k_csr_fill(const int* __restrict__ src_e, const int* __restrict__ dst_e,
                           const int* __restrict__ rowptr, int* __restrict__ fill,
                           int* __restrict__ csr_src) {
    int i = blockIdx.x * blockDim.x + threadIdx.x;
    if (i < EP) {
        int d = dst_e[i];
        int pos = atomicAdd(&fill[d], 1);
        csr_src[rowptr[d] + pos] = src_e[i];
    }
}

// ---------------- input projection (float4 over columns) ----------------
__global__ void k_input_fc(const float* __restrict__ xseq, const float4* __restrict__ Win4,
                           const float4* __restrict__ b_in4, float4* __restrict__ x0) {
    int idx = blockIdx.x * 256 + threadIdx.x;   // ROWS*16 threads
    int r = idx >> 4, c4 = idx & 15;
    float4 acc = b_in4[c4];
    #pragma unroll
    for (int k = 0; k < FIN; k++) {
        float xv = xseq[r * FIN + k];
        float4 w = Win4[k * 16 + c4];
        acc.x += xv * w.x; acc.y += xv * w.y; acc.z += xv * w.z; acc.w += xv * w.w;
    }
    x0[idx] = acc;
}

// ---------------- GAT: h = x @ W, plus ls/ld attention dots ----------------
__global__ __launch_bounds__(256) void k_gat_h(const float4* __restrict__ x4, const float4* __restrict__ W4,
                                               const float* __restrict__ asrc, const float* __restrict__ adst,
                                               float* __restrict__ h, float* __restrict__ ls, float* __restrict__ ld) {
    __shared__ float xs[64 * 68];                 // [k][row] transposed, pitch 68
    __shared__ __align__(16) float ws[64 * 64];   // [k][c]
    int r0 = blockIdx.x * 64;
    int head = blockIdx.y;
    int c0 = head * 64;
    int tid = threadIdx.x;
    for (int q = tid; q < 1024; q += 256) {
        int a = q >> 4, kq = q & 15;
        float4 v = x4[(size_t)(r0 + a) * 16 + kq];
        xs[(kq * 4 + 0) * 68 + a] = v.x;
        xs[(kq * 4 + 1) * 68 + a] = v.y;
        xs[(kq * 4 + 2) * 68 + a] = v.z;
        xs[(kq * 4 + 3) * 68 + a] = v.w;
    }
    for (int idx = tid; idx < 1024; idx += 256) {
        int k = idx >> 4, j = idx & 15;
        *reinterpret_cast<float4*>(&ws[k * 64 + j * 4]) = W4[(size_t)k * 64 + head * 16 + j];
    }
    __syncthreads();
    int tx = tid & 15, ty = tid >> 4;
    float acc[4][4] = {};
    for (int k = 0; k < 64; k++) {
        float4 xv = *reinterpret_cast<const float4*>(&xs[k * 68 + ty * 4]);
        float4 w4 = *reinterpret_cast<const float4*>(&ws[k * 64 + tx * 4]);
        acc[0][0] += xv.x * w4.x; acc[0][1] += xv.x * w4.y; acc[0][2] += xv.x * w4.z; acc[0][3] += xv.x * w4.w;
        acc[1][0] += xv.y * w4.x; acc[1][1] += xv.y * w4.y; acc[1][2] += xv.y * w4.z; acc[1][3] += xv.y * w4.w;
        acc[2][0] += xv.z * w4.x; acc[2][1] += xv.z * w4.y; acc[2][2] += xv.z * w4.z; acc[2][3] += xv.z * w4.w;
        acc[3][0] += xv.w * w4.x; acc[3][1] += xv.w * w4.y; acc[3][2] += xv.w * w4.z; acc[3][3] += xv.w * w4.w;
    }
    #pragma unroll
    for (int i = 0; i < 4; i++) {
        float4 v = make_float4(acc[i][0], acc[i][1], acc[i][2], acc[i][3]);
        *reinterpret_cast<float4*>(&h[(size_t)(r0 + ty * 4 + i) * HCOL + c0 + tx * 4]) = v;
    }
    float a0 = asrc[c0 + tx * 4 + 0], a1 = asrc[c0 + tx * 4 + 1];
    float a2 = asrc[c0 + tx * 4 + 2], a3 = asrc[c0 + tx * 4 + 3];
    float d0 = adst[c0 + tx * 4 + 0], d1 = adst[c0 + tx * 4 + 1];
    float d2 = adst[c0 + tx * 4 + 2], d3 = adst[c0 + tx * 4 + 3];
    #pragma unroll
    for (int i = 0; i < 4; i++) {
        float ps = acc[i][0] * a0 + acc[i][1] * a1 + acc[i][2] * a2 + acc[i][3] * a3;
        float pd = acc[i][0] * d0 + acc[i][1] * d1 + acc[i][2] * d2 + acc[i][3] * d3;
        #pragma unroll
        for (int m = 1; m < 16; m <<= 1) {
            ps += __shfl_xor(ps, m, 64);
            pd += __shfl_xor(pd, m, 64);
        }
        if (tx == 0) {
            ls[(size_t)(r0 + ty * 4 + i) * HEADS + head] = ps;
            ld[(size_t)(r0 + ty * 4 + i) * HEADS + head] = pd;
        }
    }
}

// ---------------- fused logits + softmax + alpha, per (g,n), 4 heads as float4 ----------------
__global__ __launch_bounds__(256) void k_alpha(const float4* __restrict__ ls4, const float4* __restrict__ ld4,
                                               const int* __restrict__ rowptr, const int* __restrict__ csr_src,
                                               float4* __restrict__ abuf) {
    int idx = blockIdx.x * 256 + threadIdx.x;     // GG*NNODE
    if (idx >= GG * NNODE) return;
    int g = idx / NNODE, n = idx - g * NNODE;
    int rs = rowptr[n], re = rowptr[n + 1];
    int dg = re - rs;
    float4 ldv = ld4[(size_t)g * NNODE + n];
    const float4* lsg = ls4 + (size_t)g * NNODE;
    float4* out = abuf + (size_t)g * EP;
    if (dg <= 16) {
        int sv[16];
        float4 v[16];
        #pragma unroll
        for (int u = 0; u < 16; u++) sv[u] = (u < dg) ? csr_src[rs + u] : 0;
        #pragma unroll
        for (int u = 0; u < 16; u++) {
            if (u < dg) {
                float4 t = lsg[sv[u]];
                t.x += ldv.x; t.y += ldv.y; t.z += ldv.z; t.w += ldv.w;
                t.x = t.x >= 0.f ? t.x : 0.2f * t.x;
                t.y = t.y >= 0.f ? t.y : 0.2f * t.y;
                t.z = t.z >= 0.f ? t.z : 0.2f * t.z;
                t.w = t.w >= 0.f ? t.w : 0.2f * t.w;
                v[u] = t;
            }
        }
        float4 m = make_float4(-1e30f, -1e30f, -1e30f, -1e30f);
        #pragma unroll
        for (int u = 0; u < 16; u++) {
            if (u < dg) {
                m.x = fmaxf(m.x, v[u].x); m.y = fmaxf(m.y, v[u].y);
                m.z = fmaxf(m.z, v[u].z); m.w = fmaxf(m.w, v[u].w);
            }
        }
        float4 den = make_float4(0.f, 0.f, 0.f, 0.f);
        #pragma unroll
        for (int u = 0; u < 16; u++) {
            if (u < dg) {
                v[u].x = expf(v[u].x - m.x); den.x += v[u].x;
                v[u].y = expf(v[u].y - m.y); den.y += v[u].y;
                v[u].z = expf(v[u].z - m.z); den.z += v[u].z;
                v[u].w = expf(v[u].w - m.w); den.w += v[u].w;
            }
        }
        float4 inv = make_float4(1.f / (den.x + 1e-16f), 1.f / (den.y + 1e-16f),
                                 1.f / (den.z + 1e-16f), 1.f / (den.w + 1e-16f));
        #pragma unroll
        for (int u = 0; u < 16; u++) {
            if (u < dg) {
                float4 t = make_float4(v[u].x * inv.x, v[u].y * inv.y, v[u].z * inv.z, v[u].w * inv.w);
                out[rs + u] = t;
            }
        }
    } else {
        float4 m = make_float4(-1e30f, -1e30f, -1e30f, -1e30f);
        for (int j = rs; j < re; j++) {
            float4 t = lsg[csr_src[j]];
            t.x += ldv.x; t.y += ldv.y; t.z += ldv.z; t.w += ldv.w;
            t.x = t.x >= 0.f ? t.x : 0.2f * t.x;
            t.y = t.y >= 0.f ? t.y : 0.2f * t.y;
            t.z = t.z >= 0.f ? t.z : 0.2f * t.z;
            t.w = t.w >= 0.f ? t.w : 0.2f * t.w;
            out[j] = t;
            m.x = fmaxf(m.x, t.x); m.y = fmaxf(m.y, t.y);
            m.z = fmaxf(m.z, t.z); m.w = fmaxf(m.w, t.w);
        }
        float4 den = make_float4(0.f, 0.f, 0.f, 0.f);
        for (int j = rs; j < re; j++) {
            float4 t = out[j];
            t.x = expf(t.x - m.x); den.x += t.x;
            t.y = expf(t.y - m.y); den.y += t.y;
            t.z = expf(t.z - m.z); den.z += t.z;
            t.w = expf(t.w - m.w); den.w += t.w;
            out[j] = t;
        }
        float4 inv = make_float4(1.f / (den.x + 1e-16f), 1.f / (den.y + 1e-16f),
                                 1.f / (den.z + 1e-16f), 1.f / (den.w + 1e-16f));
        for (int j = rs; j < re; j++) {
            float4 t = out[j];
            t.x *= inv.x; t.y *= inv.y; t.z *= inv.z; t.w *= inv.w;
            out[j] = t;
        }
    }
}

// ---------------- GAT aggregate: one wave per (g,n), lane = head*16+c4 ----------------
__global__ __launch_bounds__(256) void k_agg(const float4* __restrict__ h4, const float* __restrict__ alpha,
                                             const int* __restrict__ rowptr, const int* __restrict__ csr_src,
                                             const float4* __restrict__ bg4, float4* __restrict__ xout4) {
    __shared__ int s_lds[1024];
    int n = blockIdx.x;
    int tid = threadIdx.x;
    int wid = tid >> 6, lane = tid & 63;
    int g = blockIdx.y * 4 + wid;
    int head = lane >> 4, c4 = lane & 15;
    int rs = rowptr[n], re = rowptr[n + 1];
    int dg = re - rs;
    for (int j = tid; j < dg; j += 256) s_lds[j] = csr_src[rs + j];
    __syncthreads();
    const float* ag = alpha + ((size_t)g * EP + rs) * HEADS + head;
    const float4* hg = h4 + (size_t)g * NNODE * 64 + head * 16 + c4;
    float4 acc = make_float4(0.f, 0.f, 0.f, 0.f);
    for (int j0 = 0; j0 < dg; j0 += 16) {
        int cnt = dg - j0;
        int sv[16]; float av[16];
        #pragma unroll
        for (int u = 0; u < 16; u++) {
            bool ok = u < cnt;
            sv[u] = ok ? s_lds[j0 + u] : 0;
            av[u] = ok ? ag[(size_t)(j0 + u) * HEADS] : 0.f;
        }
        float4 hv[16];
        #pragma unroll
        for (int u = 0; u < 16; u++) hv[u] = hg[(size_t)sv[u] * 64];
        #pragma unroll
        for (int u = 0; u < 16; u++) {
            acc.x += av[u] * hv[u].x;
            acc.y += av[u] * hv[u].y;
            acc.z += av[u] * hv[u].z;
            acc.w += av[u] * hv[u].w;
        }
    }
    #pragma unroll
    for (int m = 16; m < 64; m <<= 1) {
        acc.x += __shfl_xor(acc.x, m, 64);
        acc.y += __shfl_xor(acc.y, m, 64);
        acc.z += __shfl_xor(acc.z, m, 64);
        acc.w += __shfl_xor(acc.w, m, 64);
    }
    if (head == 0) {
        float4 b = bg4[c4];
        acc.x = acc.x * 0.25f + b.x;
        acc.y = acc.y * 0.25f + b.y;
        acc.z = acc.z * 0.25f + b.z;
        acc.w = acc.w * 0.25f + b.w;
        acc.x = acc.x > 0.f ? acc.x : expm1f(acc.x);
        acc.y = acc.y > 0.f ? acc.y : expm1f(acc.y);
        acc.z = acc.z > 0.f ? acc.z : expm1f(acc.z);
        acc.w = acc.w > 0.f ? acc.w : expm1f(acc.w);
        xout4[((size_t)g * NNODE + n) * 16 + c4] = acc;
    }
}

// ---------------- GRU input GEMM: split-K (500) x 3 col-groups, 16 split buffers ----------------
__global__ void k_gip_zero(float* __restrict__ gip) {
    gip[blockIdx.x * 256 + threadIdx.x] = 0.f;   // NSPLIT*GG*GOUT elements
}

__global__ __launch_bounds__(256) void k_gi_gemm(const float* __restrict__ x, const float* __restrict__ W_ih,
                                                 float* __restrict__ gip) {
    __shared__ float xs[32 * 68];   // [kk][row]
    __shared__ float ws[32 * 68];   // [kk][col]
    int k0 = blockIdx.x * GIK;
    int c0 = blockIdx.y * 64;
    int tid = threadIdx.x;
    int tx = tid & 15, ty = tid >> 4;
    float acc[4][4] = {};
    for (int kt = 0; kt < GIK / 32; kt++) {
        int kb = k0 + kt * 32;
        for (int q = tid; q < 512; q += 256) {
            int r = q >> 3, kq = q & 7;
            float4 v = *reinterpret_cast<const float4*>(&x[(size_t)r * KGI + kb + kq * 4]);
            xs[(kq * 4 + 0) * 68 + r] = v.x;
            xs[(kq * 4 + 1) * 68 + r] = v.y;
            xs[(kq * 4 + 2) * 68 + r] = v.z;
            xs[(kq * 4 + 3) * 68 + r] = v.w;
        }
        for (int q = tid; q < 512; q += 256) {
            int c = q >> 3, kq = q & 7;
            float4 v = *reinterpret_cast<const float4*>(&W_ih[(size_t)(c0 + c) * KGI + kb + kq * 4]);
            ws[(kq * 4 + 0) * 68 + c] = v.x;
            ws[(kq * 4 + 1) * 68 + c] = v.y;
            ws[(kq * 4 + 2) * 68 + c] = v.z;
            ws[(kq * 4 + 3) * 68 + c] = v.w;
        }
        __syncthreads();
        for (int kk = 0; kk < 32; kk++) {
            float4 xv = *reinterpret_cast<const float4*>(&xs[kk * 68 + ty * 4]);
            float4 wv = *reinterpret_cast<const float4*>(&ws[kk * 68 + tx * 4]);
            acc[0][0] += xv.x * wv.x; acc[0][1] += xv.x * wv.y; acc[0][2] += xv.x * wv.z; acc[0][3] += xv.x * wv.w;
            acc[1][0] += xv.y * wv.x; acc[1][1] += xv.y * wv.y; acc[1][2] += xv.y * wv.z; acc[1][3] += xv.y * wv.w;
            acc[2][0] += xv.z * wv.x; acc[2][1] += xv.z * wv.y; acc[2][2] += xv.z * wv.z; acc[2][3] += xv.z * wv.w;
            acc[3][0] += xv.w * wv.x; acc[3][1] += xv.w * wv.y; acc[3][2] += xv.w * wv.z; acc[3][3] += xv.w * wv.w;
        }
        __syncthreads();
    }
    float* out = gip + (size_t)(blockIdx.x & (NSPLIT - 1)) * (GG * GOUT);
    #pragma unroll
    for (int i = 0; i < 4; i++)
        #pragma unroll
        for (int q = 0; q < 4; q++)
            atomicAdd(&out[(ty * 4 + i) * GOUT + c0 + tx * 4 + q], acc[i][q]);
}

__global__ void k_gi_reduce(const float* __restrict__ gip, const float* __restrict__ b_ih,
                            float* __restrict__ gi) {
    int idx = blockIdx.x * 256 + threadIdx.x;    // GG*GOUT
    if (idx >= GG * GOUT) return;
    float a = b_ih[idx % GOUT];
    #pragma unroll
    for (int s = 0; s < NSPLIT; s++) a += gip[(size_t)s * (GG * GOUT) + idx];
    gi[idx] = a;
}

// ---------------- GRU scan (single block) ----------------
__global__ __launch_bounds__(256) void k_gru(const float* __restrict__ gi, const float* __restrict__ W_hh,
                                             const float* __restrict__ b_hh, float* __restrict__ hT) {
    __shared__ float Wt[64 * 192];   // [c][j] transposed
    __shared__ float hs[4][64];
    __shared__ float gh[4][192];
    int tid = threadIdx.x;
    for (int idx = tid; idx < 192 * 64; idx += 256) {
        int j = idx >> 6, c = idx & 63;
        Wt[c * 192 + j] = W_hh[idx];
    }
    int b_ = tid >> 6, c_ = tid & 63;
    hs[b_][c_] = 0.f;
    __syncthreads();
    for (int t = 0; t < TT; t++) {
        #pragma unroll
        for (int q = 0; q < 3; q++) {
            int p = tid + 256 * q;
            int bb = p / GOUT, j = p % GOUT;
            float a = b_hh[j];
            for (int c = 0; c < 64; c++) a += hs[bb][c] * Wt[c * 192 + j];
            gh[bb][j] = a;
        }
        __syncthreads();
        int row = (b_ * TT + t) * GOUT;
        float ir = gi[row + c_], iz = gi[row + 64 + c_], in_ = gi[row + 128 + c_];
        float r = 1.f / (1.f + expf(-(ir + gh[b_][c_])));
        float z = 1.f / (1.f + expf(-(iz + gh[b_][64 + c_])));
        float nv = tanhf(in_ + r * gh[b_][128 + c_]);
        float hn = (1.f - z) * nv + z * hs[b_][c_];
        hs[b_][c_] = hn;
        __syncthreads();
    }
    hT[tid] = hs[b_][c_];
}

// ---------------- final FC ----------------
__global__ void k_final(const float* __restrict__ hT, const float* __restrict__ W_fc,
                        const float* __restrict__ b_fc, float* __restrict__ out) {
    int idx = blockIdx.x * 256 + threadIdx.x;
    if (idx >= NB * NNODE) return;
    int b = idx / NNODE, n = idx % NNODE;
    float acc = b_fc[n];
    #pragma unroll
    for (int c = 0; c < HID; c++) acc += hT[b * HID + c] * W_fc[c * NNODE + n];
    out[idx] = acc;
}

extern "C" void kernel_launch(void* const* d_in, const int* in_sizes, int n_in,
                              void* d_out, int out_size, void* d_ws, size_t ws_size,
                              hipStream_t stream) {
    const float* x_seq  = (const float*)d_in[0];
    const int*   eidx   = (const int*)  d_in[1];
    // d_in[2] edge_weight: unused by GATConv
    const float* W_in   = (const float*)d_in[3];
    const float* b_in   = (const float*)d_in[4];
    const float* Wg     = (const float*)d_in[5];
    const float* a_src  = (const float*)d_in[6];
    const float* a_dst  = (const float*)d_in[7];
    const float* bg     = (const float*)d_in[8];
    const float* W_ih   = (const float*)d_in[9];
    const float* W_hh   = (const float*)d_in[10];
    const float* b_ih   = (const float*)d_in[11];
    const float* b_hh   = (const float*)d_in[12];
    const float* W_fc   = (const float*)d_in[13];
    const float* b_fc   = (const float*)d_in[14];
    float* out = (float*)d_out;

    float* wsf = (float*)d_ws;
    size_t off = 0;
    float* x0     = wsf + off; off += (size_t)ROWS * HID;      // 4,096,000
    float* x1     = wsf + off; off += (size_t)ROWS * HID;      // 4,096,000
    float* hbuf   = wsf + off; off += (size_t)ROWS * HCOL;     // 16,384,000
    float* lsb    = wsf + off; off += (size_t)ROWS * HEADS;    // 256,000
    float* ldb    = wsf + off; off += (size_t)ROWS * HEADS;    // 256,000
    float* abuf   = wsf + off; off += (size_t)GG * EP * HEADS; // 2,304,000
    float* gip    = wsf + off; off += (size_t)NSPLIT * GG * GOUT; // 196,608
    float* gib    = wsf + off; off += GG * GOUT;               // 12,288
    float* hTb    = wsf + off; off += 256;
    int* ib = (int*)(wsf + off);
    int* src_e   = ib;           ib += EP;
    int* dst_e   = ib;           ib += EP;
    int* rowptr  = ib;           ib += NNODE + 1;
    int* csr_src = ib;           ib += EP;
    int* deg     = ib;           ib += NNODE;
    int* fill    = ib;           ib += NNODE;

    k_build_edges<<<(EP + 255) / 256, 256, 0, stream>>>(eidx, src_e, dst_e, deg, fill);
    k_csr_count<<<(EP + 255) / 256, 256, 0, stream>>>(dst_e, deg);
    k_csr_scan<<<1, 256, 0, stream>>>(deg, rowptr);
    k_csr_fill<<<(EP + 255) / 256, 256, 0, stream>>>(src_e, dst_e, rowptr, fill, csr_src);

    k_input_fc<<<ROWS * 16 / 256, 256, 0, stream>>>(x_seq, (const float4*)W_in, (const float4*)b_in,
                                                    (float4*)x0);

    const float* xcur = x0;
    float* xnext = x1;
    for (int l = 0; l < NL; l++) {
        k_gat_h<<<dim3(ROWS / 64, HEADS), 256, 0, stream>>>(
            (const float4*)xcur, (const float4*)(Wg + (size_t)l * HID * HCOL),
            a_src + (size_t)l * HEADS * HID, a_dst + (size_t)l * HEADS * HID, hbuf, lsb, ldb);
        k_alpha<<<(GG * NNODE + 255) / 256, 256, 0, stream>>>(
            (const float4*)lsb, (const float4*)ldb, rowptr, csr_src, (float4*)abuf);
        k_agg<<<dim3(NNODE, GG / 4), 256, 0, stream>>>(
            (const float4*)hbuf, abuf, rowptr, csr_src,
            (const float4*)(bg + (size_t)l * HID), (float4*)xnext);
        const float* tmp = xcur; xcur = xnext; xnext = (float*)tmp;
    }

    k_gip_zero<<<NSPLIT * GG * GOUT / 256, 256, 0, stream>>>(gip);
    k_gi_gemm<<<dim3(KGI / GIK, 3), 256, 0, stream>>>(xcur, W_ih, gip);
    k_gi_reduce<<<(GG * GOUT + 255) / 256, 256, 0, stream>>>(gip, b_ih, gib);
    k_gru<<<1, 256, 0, stream>>>(gib, W_hh, b_hh, hTb);
    k_final<<<(NB * NNODE + 255) / 256, 256, 0, stream>>>(hTb, W_fc, b_fc, out);
}

// Round 5
// 911.418 us; speedup vs baseline: 1.1339x; 1.1339x over previous
//
#include <hip/hip_runtime.h>
#include <math.h>

#define NB 4
#define TT 16
#define NNODE 1000
#define FIN 8
#define EE 8000
#define EP 9000          // E + N self loops
#define HID 64
#define HEADS 4
#define NL 5
#define GG (NB*TT)       // 64 graphs
#define ROWS (GG*NNODE)  // 64000
#define HCOL (HEADS*HID) // 256
#define KGI (NNODE*HID)  // 64000
#define GOUT 192         // 3*HID
#define GIK 128          // K-slice per gi-gemm block
#define KSPLIT (KGI/GIK) // 500 partial slabs
#define GOSZ (GG*GOUT)   // 12288

// ---------------- edge prep ----------------
__global__ void k_build_edges(const int* __restrict__ eidx, int* __restrict__ src_e,
                              int* __restrict__ dst_e, int* __restrict__ deg, int* __restrict__ fill) {
    int i = blockIdx.x * blockDim.x + threadIdx.x;
    if (i < EP) {
        int s, d;
        if (i < EE) { s = eidx[i]; d = eidx[EE + i]; }
        else { s = i - EE; d = i - EE; }
        src_e[i] = s; dst_e[i] = d;
    }
    if (i < NNODE) { deg[i] = 0; fill[i] = 0; }
}

__global__ void k_csr_count(const int* __restrict__ dst_e, int* __restrict__ deg) {
    int i = blockIdx.x * blockDim.x + threadIdx.x;
    if (i < EP) atomicAdd(&deg[dst_e[i]], 1);
}

// parallel inclusive scan over 1024 (padded) in LDS
__global__ __launch_bounds__(256) void k_csr_scan(const int* __restrict__ deg, int* __restrict__ rowptr) {
    __shared__ int s[1024];
    int tid = threadIdx.x;
    for (int i = tid; i < 1024; i += 256) s[i] = (i < NNODE) ? deg[i] : 0;
    __syncthreads();
    for (int off = 1; off < 1024; off <<= 1) {
        int t[4];
        #pragma unroll
        for (int q = 0; q < 4; q++) { int i = tid + 256 * q; t[q] = (i >= off) ? s[i - off] : 0; }
        __syncthreads();
        #pragma unroll
        for (int q = 0; q < 4; q++) { int i = tid + 256 * q; s[i] += t[q]; }
        __syncthreads();
    }
    for (int i = tid; i < NNODE; i += 256) rowptr[i + 1] = s[i];
    if (tid == 0) rowptr[0] = 0;
}

__global__ void k_csr_fill(const int* __restrict__ src_e, const int* __restrict__ dst_e,
                           const int* __restrict__ rowptr, int* __restrict__ fill,
                           int* __restrict__ csr_src) {
    int i = blockIdx.x * blockDim.x + threadIdx.x;
    if (i < EP) {
        int d = dst_e[i];
        int pos = atomicAdd(&fill[d], 1);
        csr_src[rowptr[d] + pos] = src_e[i];
    }
}

// ---------------- input projection (float4 over columns) ----------------
__global__ void k_input_fc(const float* __restrict__ xseq, const float4* __restrict__ Win4,
                           const float4* __restrict__ b_in4, float4* __restrict__ x0) {
    int idx = blockIdx.x * 256 + threadIdx.x;   // ROWS*16 threads
    int r = idx >> 4, c4 = idx & 15;
    float4 acc = b_in4[c4];
    #pragma unroll
    for (int k = 0; k < FIN; k++) {
        float xv = xseq[r * FIN + k];
        float4 w = Win4[k * 16 + c4];
        acc.x += xv * w.x; acc.y += xv * w.y; acc.z += xv * w.z; acc.w += xv * w.w;
    }
    x0[idx] = acc;
}

// ---------------- GAT: h = x @ W, plus ls/ld attention dots ----------------
__global__ __launch_bounds__(256) void k_gat_h(const float4* __restrict__ x4, const float4* __restrict__ W4,
                                               const float* __restrict__ asrc, const float* __restrict__ adst,
                                               float* __restrict__ h, float* __restrict__ ls, float* __restrict__ ld) {
    __shared__ float xs[64 * 68];                 // [k][row] transposed, pitch 68
    __shared__ __align__(16) float ws[64 * 64];   // [k][c]
    int r0 = blockIdx.x * 64;
    int head = blockIdx.y;
    int c0 = head * 64;
    int tid = threadIdx.x;
    // lane-major staging: within a wave kq is constant, row = lane -> conflict-free writes
    int a = tid & 63;
    #pragma unroll
    for (int it = 0; it < 4; it++) {
        int kq = (tid >> 6) + 4 * it;             // 0..15
        float4 v = x4[(size_t)(r0 + a) * 16 + kq];
        int k = kq * 4;
        xs[(k + 0) * 68 + a] = v.x;
        xs[(k + 1) * 68 + a] = v.y;
        xs[(k + 2) * 68 + a] = v.z;
        xs[(k + 3) * 68 + a] = v.w;
    }
    for (int idx = tid; idx < 1024; idx += 256) {
        int k = idx >> 4, j = idx & 15;
        *reinterpret_cast<float4*>(&ws[k * 64 + j * 4]) = W4[(size_t)k * 64 + head * 16 + j];
    }
    __syncthreads();
    int tx = tid & 15, ty = tid >> 4;
    float acc[4][4] = {};
    for (int k = 0; k < 64; k++) {
        float4 xv = *reinterpret_cast<const float4*>(&xs[k * 68 + ty * 4]);
        float4 w4 = *reinterpret_cast<const float4*>(&ws[k * 64 + tx * 4]);
        acc[0][0] += xv.x * w4.x; acc[0][1] += xv.x * w4.y; acc[0][2] += xv.x * w4.z; acc[0][3] += xv.x * w4.w;
        acc[1][0] += xv.y * w4.x; acc[1][1] += xv.y * w4.y; acc[1][2] += xv.y * w4.z; acc[1][3] += xv.y * w4.w;
        acc[2][0] += xv.z * w4.x; acc[2][1] += xv.z * w4.y; acc[2][2] += xv.z * w4.z; acc[2][3] += xv.z * w4.w;
        acc[3][0] += xv.w * w4.x; acc[3][1] += xv.w * w4.y; acc[3][2] += xv.w * w4.z; acc[3][3] += xv.w * w4.w;
    }
    #pragma unroll
    for (int i = 0; i < 4; i++) {
        float4 v = make_float4(acc[i][0], acc[i][1], acc[i][2], acc[i][3]);
        *reinterpret_cast<float4*>(&h[(size_t)(r0 + ty * 4 + i) * HCOL + c0 + tx * 4]) = v;
    }
    float a0 = asrc[c0 + tx * 4 + 0], a1 = asrc[c0 + tx * 4 + 1];
    float a2 = asrc[c0 + tx * 4 + 2], a3 = asrc[c0 + tx * 4 + 3];
    float d0 = adst[c0 + tx * 4 + 0], d1 = adst[c0 + tx * 4 + 1];
    float d2 = adst[c0 + tx * 4 + 2], d3 = adst[c0 + tx * 4 + 3];
    #pragma unroll
    for (int i = 0; i < 4; i++) {
        float ps = acc[i][0] * a0 + acc[i][1] * a1 + acc[i][2] * a2 + acc[i][3] * a3;
        float pd = acc[i][0] * d0 + acc[i][1] * d1 + acc[i][2] * d2 + acc[i][3] * d3;
        #pragma unroll
        for (int m = 1; m < 16; m <<= 1) {
            ps += __shfl_xor(ps, m, 64);
            pd += __shfl_xor(pd, m, 64);
        }
        if (tx == 0) {
            ls[(size_t)(r0 + ty * 4 + i) * HEADS + head] = ps;
            ld[(size_t)(r0 + ty * 4 + i) * HEADS + head] = pd;
        }
    }
}

// ---------------- fused logits + softmax + alpha, per (g,n), 4 heads as float4 ----------------
__global__ __launch_bounds__(256) void k_alpha(const float4* __restrict__ ls4, const float4* __restrict__ ld4,
                                               const int* __restrict__ rowptr, const int* __restrict__ csr_src,
                                               float4* __restrict__ abuf) {
    int idx = blockIdx.x * 256 + threadIdx.x;     // GG*NNODE
    if (idx >= GG * NNODE) return;
    int g = idx / NNODE, n = idx - g * NNODE;
    int rs = rowptr[n], re = rowptr[n + 1];
    int dg = re - rs;
    float4 ldv = ld4[(size_t)g * NNODE + n];
    const float4* lsg = ls4 + (size_t)g * NNODE;
    float4* out = abuf + (size_t)g * EP;
    if (dg <= 16) {
        int sv[16];
        float4 v[16];
        #pragma unroll
        for (int u = 0; u < 16; u++) sv[u] = (u < dg) ? csr_src[rs + u] : 0;
        #pragma unroll
        for (int u = 0; u < 16; u++) {
            if (u < dg) {
                float4 t = lsg[sv[u]];
                t.x += ldv.x; t.y += ldv.y; t.z += ldv.z; t.w += ldv.w;
                t.x = t.x >= 0.f ? t.x : 0.2f * t.x;
                t.y = t.y >= 0.f ? t.y : 0.2f * t.y;
                t.z = t.z >= 0.f ? t.z : 0.2f * t.z;
                t.w = t.w >= 0.f ? t.w : 0.2f * t.w;
                v[u] = t;
            }
        }
        float4 m = make_float4(-1e30f, -1e30f, -1e30f, -1e30f);
        #pragma unroll
        for (int u = 0; u < 16; u++) {
            if (u < dg) {
                m.x = fmaxf(m.x, v[u].x); m.y = fmaxf(m.y, v[u].y);
                m.z = fmaxf(m.z, v[u].z); m.w = fmaxf(m.w, v[u].w);
            }
        }
        float4 den = make_float4(0.f, 0.f, 0.f, 0.f);
        #pragma unroll
        for (int u = 0; u < 16; u++) {
            if (u < dg) {
                v[u].x = expf(v[u].x - m.x); den.x += v[u].x;
                v[u].y = expf(v[u].y - m.y); den.y += v[u].y;
                v[u].z = expf(v[u].z - m.z); den.z += v[u].z;
                v[u].w = expf(v[u].w - m.w); den.w += v[u].w;
            }
        }
        float4 inv = make_float4(1.f / (den.x + 1e-16f), 1.f / (den.y + 1e-16f),
                                 1.f / (den.z + 1e-16f), 1.f / (den.w + 1e-16f));
        #pragma unroll
        for (int u = 0; u < 16; u++) {
            if (u < dg) {
                float4 t = make_float4(v[u].x * inv.x, v[u].y * inv.y, v[u].z * inv.z, v[u].w * inv.w);
                out[rs + u] = t;
            }
        }
    } else {
        float4 m = make_float4(-1e30f, -1e30f, -1e30f, -1e30f);
        for (int j = rs; j < re; j++) {
            float4 t = lsg[csr_src[j]];
            t.x += ldv.x; t.y += ldv.y; t.z += ldv.z; t.w += ldv.w;
            t.x = t.x >= 0.f ? t.x : 0.2f * t.x;
            t.y = t.y >= 0.f ? t.y : 0.2f * t.y;
            t.z = t.z >= 0.f ? t.z : 0.2f * t.z;
            t.w = t.w >= 0.f ? t.w : 0.2f * t.w;
            out[j] = t;
            m.x = fmaxf(m.x, t.x); m.y = fmaxf(m.y, t.y);
            m.z = fmaxf(m.z, t.z); m.w = fmaxf(m.w, t.w);
        }
        float4 den = make_float4(0.f, 0.f, 0.f, 0.f);
        for (int j = rs; j < re; j++) {
            float4 t = out[j];
            t.x = expf(t.x - m.x); den.x += t.x;
            t.y = expf(t.y - m.y); den.y += t.y;
            t.z = expf(t.z - m.z); den.z += t.z;
            t.w = expf(t.w - m.w); den.w += t.w;
            out[j] = t;
        }
        float4 inv = make_float4(1.f / (den.x + 1e-16f), 1.f / (den.y + 1e-16f),
                                 1.f / (den.z + 1e-16f), 1.f / (den.w + 1e-16f));
        for (int j = rs; j < re; j++) {
            float4 t = out[j];
            t.x *= inv.x; t.y *= inv.y; t.z *= inv.z; t.w *= inv.w;
            out[j] = t;
        }
    }
}

// ---------------- GAT aggregate: one wave per (g,n), lane = head*16+c4 ----------------
__global__ __launch_bounds__(256) void k_agg(const float4* __restrict__ h4, const float* __restrict__ alpha,
                                             const int* __restrict__ rowptr, const int* __restrict__ csr_src,
                                             const float4* __restrict__ bg4, float4* __restrict__ xout4) {
    __shared__ int s_lds[1024];
    int n = blockIdx.x;
    int tid = threadIdx.x;
    int wid = tid >> 6, lane = tid & 63;
    int g = blockIdx.y * 4 + wid;
    int head = lane >> 4, c4 = lane & 15;
    int rs = rowptr[n], re = rowptr[n + 1];
    int dg = re - rs;
    for (int j = tid; j < dg; j += 256) s_lds[j] = csr_src[rs + j];
    __syncthreads();
    const float* ag = alpha + ((size_t)g * EP + rs) * HEADS + head;
    const float4* hg = h4 + (size_t)g * NNODE * 64 + head * 16 + c4;
    float4 acc = make_float4(0.f, 0.f, 0.f, 0.f);
    for (int j0 = 0; j0 < dg; j0 += 16) {
        int cnt = dg - j0;
        int sv[16]; float av[16];
        #pragma unroll
        for (int u = 0; u < 16; u++) {
            bool ok = u < cnt;
            sv[u] = ok ? s_lds[j0 + u] : 0;
            av[u] = ok ? ag[(size_t)(j0 + u) * HEADS] : 0.f;
        }
        float4 hv[16];
        #pragma unroll
        for (int u = 0; u < 16; u++) hv[u] = hg[(size_t)sv[u] * 64];
        #pragma unroll
        for (int u = 0; u < 16; u++) {
            acc.x += av[u] * hv[u].x;
            acc.y += av[u] * hv[u].y;
            acc.z += av[u] * hv[u].z;
            acc.w += av[u] * hv[u].w;
        }
    }
    #pragma unroll
    for (int m = 16; m < 64; m <<= 1) {
        acc.x += __shfl_xor(acc.x, m, 64);
        acc.y += __shfl_xor(acc.y, m, 64);
        acc.z += __shfl_xor(acc.z, m, 64);
        acc.w += __shfl_xor(acc.w, m, 64);
    }
    if (head == 0) {
        float4 b = bg4[c4];
        acc.x = acc.x * 0.25f + b.x;
        acc.y = acc.y * 0.25f + b.y;
        acc.z = acc.z * 0.25f + b.z;
        acc.w = acc.w * 0.25f + b.w;
        acc.x = acc.x > 0.f ? acc.x : expm1f(acc.x);
        acc.y = acc.y > 0.f ? acc.y : expm1f(acc.y);
        acc.z = acc.z > 0.f ? acc.z : expm1f(acc.z);
        acc.w = acc.w > 0.f ? acc.w : expm1f(acc.w);
        xout4[((size_t)g * NNODE + n) * 16 + c4] = acc;
    }
}

// ---------------- GRU input GEMM: 500 K-slices, full 64x192 tile/block, no atomics ----------------
__global__ __launch_bounds__(256) void k_gi_gemm(const float* __restrict__ x, const float* __restrict__ W_ih,
                                                 float* __restrict__ gip) {
    __shared__ float xs[32 * 68];    // [kk][row], pitch 68
    __shared__ float ws[32 * 196];   // [kk][col 0..191], pitch 196
    int k0 = blockIdx.x * GIK;
    int tid = threadIdx.x;
    int lane = tid & 63;
    int wv = tid >> 6;               // wave id 0..3 (kq base, uniform per wave)
    int tx = tid & 15, ty = tid >> 4;
    float4 accs[4][3];
    #pragma unroll
    for (int i = 0; i < 4; i++)
        #pragma unroll
        for (int j = 0; j < 3; j++) accs[i][j] = make_float4(0.f, 0.f, 0.f, 0.f);

    for (int kt = 0; kt < GIK / 32; kt++) {
        int kb = k0 + kt * 32;
        // stage x[64 rows][32 k] -> xs[k][row]; lane-major: conflict-free transposed writes
        #pragma unroll
        for (int it = 0; it < 2; it++) {
            int kq = wv + 4 * it;    // 0..7, uniform per wave
            float4 v = *reinterpret_cast<const float4*>(&x[(size_t)lane * KGI + kb + kq * 4]);
            int k = kq * 4;
            xs[(k + 0) * 68 + lane] = v.x;
            xs[(k + 1) * 68 + lane] = v.y;
            xs[(k + 2) * 68 + lane] = v.z;
            xs[(k + 3) * 68 + lane] = v.w;
        }
        // stage W_ih[192 cols][32 k] -> ws[k][col]
        #pragma unroll
        for (int cg = 0; cg < 3; cg++) {
            #pragma unroll
            for (int it = 0; it < 2; it++) {
                int kq = wv + 4 * it;
                int c = cg * 64 + lane;
                float4 v = *reinterpret_cast<const float4*>(&W_ih[(size_t)c * KGI + kb + kq * 4]);
                int k = kq * 4;
                ws[(k + 0) * 196 + c] = v.x;
                ws[(k + 1) * 196 + c] = v.y;
                ws[(k + 2) * 196 + c] = v.z;
                ws[(k + 3) * 196 + c] = v.w;
            }
        }
        __syncthreads();
        for (int kk = 0; kk < 32; kk++) {
            float4 xv = *reinterpret_cast<const float4*>(&xs[kk * 68 + ty * 4]);
            float4 w0 = *reinterpret_cast<const float4*>(&ws[kk * 196 + tx * 4]);
            float4 w1 = *reinterpret_cast<const float4*>(&ws[kk * 196 + 64 + tx * 4]);
            float4 w2 = *reinterpret_cast<const float4*>(&ws[kk * 196 + 128 + tx * 4]);
            #pragma unroll
            for (int i = 0; i < 4; i++) {
                float xi = (i == 0) ? xv.x : (i == 1) ? xv.y : (i == 2) ? xv.z : xv.w;
                accs[i][0].x += xi * w0.x; accs[i][0].y += xi * w0.y; accs[i][0].z += xi * w0.z; accs[i][0].w += xi * w0.w;
                accs[i][1].x += xi * w1.x; accs[i][1].y += xi * w1.y; accs[i][1].z += xi * w1.z; accs[i][1].w += xi * w1.w;
                accs[i][2].x += xi * w2.x; accs[i][2].y += xi * w2.y; accs[i][2].z += xi * w2.z; accs[i][2].w += xi * w2.w;
            }
        }
        __syncthreads();
    }
    float* out = gip + (size_t)blockIdx.x * GOSZ;
    #pragma unroll
    for (int i = 0; i < 4; i++)
        #pragma unroll
        for (int j = 0; j < 3; j++)
            *reinterpret_cast<float4*>(&out[(ty * 4 + i) * GOUT + j * 64 + tx * 4]) = accs[i][j];
}

__global__ void k_gi_reduce1(const float* __restrict__ gip, float* __restrict__ gip2) {
    int idx = blockIdx.x * 256 + threadIdx.x;     // 0..GOSZ-1
    const float* p = gip + (size_t)blockIdx.y * 50 * GOSZ + idx;
    float a = 0.f;
    #pragma unroll 5
    for (int s = 0; s < 50; s++) a += p[(size_t)s * GOSZ];
    gip2[blockIdx.y * GOSZ + idx] = a;
}

__global__ void k_gi_reduce2(const float* __restrict__ gip2, const float* __restrict__ b_ih,
                             float* __restrict__ gi) {
    int idx = blockIdx.x * 256 + threadIdx.x;
    float a = b_ih[idx % GOUT];
    #pragma unroll
    for (int y = 0; y < 10; y++) a += gip2[(size_t)y * GOSZ + idx];
    gi[idx] = a;
}

// ---------------- GRU scan (single block) ----------------
__global__ __launch_bounds__(256) void k_gru(const float* __restrict__ gi, const float* __restrict__ W_hh,
                                             const float* __restrict__ b_hh, float* __restrict__ hT) {
    __shared__ float Wt[64 * 192];   // [c][j] transposed
    __shared__ float hs[4][64];
    __shared__ float gh[4][192];
    int tid = threadIdx.x;
    for (int idx = tid; idx < 192 * 64; idx += 256) {
        int j = idx >> 6, c = idx & 63;
        Wt[c * 192 + j] = W_hh[idx];
    }
    int b_ = tid >> 6, c_ = tid & 63;
    hs[b_][c_] = 0.f;
    __syncthreads();
    for (int t = 0; t < TT; t++) {
        #pragma unroll
        for (int q = 0; q < 3; q++) {
            int p = tid + 256 * q;
            int bb = p / GOUT, j = p % GOUT;
            float a = b_hh[j];
            for (int c = 0; c < 64; c++) a += hs[bb][c] * Wt[c * 192 + j];
            gh[bb][j] = a;
        }
        __syncthreads();
        int row = (b_ * TT + t) * GOUT;
        float ir = gi[row + c_], iz = gi[row + 64 + c_], in_ = gi[row + 128 + c_];
        float r = 1.f / (1.f + expf(-(ir + gh[b_][c_])));
        float z = 1.f / (1.f + expf(-(iz + gh[b_][64 + c_])));
        float nv = tanhf(in_ + r * gh[b_][128 + c_]);
        float hn = (1.f - z) * nv + z * hs[b_][c_];
        hs[b_][c_] = hn;
        __syncthreads();
    }
    hT[tid] = hs[b_][c_];
}

// ---------------- final FC ----------------
__global__ void k_final(const float* __restrict__ hT, const float* __restrict__ W_fc,
                        const float* __restrict__ b_fc, float* __restrict__ out) {
    int idx = blockIdx.x * 256 + threadIdx.x;
    if (idx >= NB * NNODE) return;
    int b = idx / NNODE, n = idx % NNODE;
    float acc = b_fc[n];
    #pragma unroll
    for (int c = 0; c < HID; c++) acc += hT[b * HID + c] * W_fc[c * NNODE + n];
    out[idx] = acc;
}

extern "C" void kernel_launch(void* const* d_in, const int* in_sizes, int n_in,
                              void* d_out, int out_size, void* d_ws, size_t ws_size,
                              hipStream_t stream) {
    const float* x_seq  = (const float*)d_in[0];
    const int*   eidx   = (const int*)  d_in[1];
    // d_in[2] edge_weight: unused by GATConv
    const float* W_in   = (const float*)d_in[3];
    const float* b_in   = (const float*)d_in[4];
    const float* Wg     = (const float*)d_in[5];
    const float* a_src  = (const float*)d_in[6];
    const float* a_dst  = (const float*)d_in[7];
    const float* bg     = (const float*)d_in[8];
    const float* W_ih   = (const float*)d_in[9];
    const float* W_hh   = (const float*)d_in[10];
    const float* b_ih   = (const float*)d_in[11];
    const float* b_hh   = (const float*)d_in[12];
    const float* W_fc   = (const float*)d_in[13];
    const float* b_fc   = (const float*)d_in[14];
    float* out = (float*)d_out;

    float* wsf = (float*)d_ws;
    size_t off = 0;
    float* x0     = wsf + off; off += (size_t)ROWS * HID;      // 4,096,000
    float* x1     = wsf + off; off += (size_t)ROWS * HID;      // 4,096,000
    float* hbuf   = wsf + off; off += (size_t)ROWS * HCOL;     // 16,384,000
    float* lsb    = wsf + off; off += (size_t)ROWS * HEADS;    // 256,000
    float* ldb    = wsf + off; off += (size_t)ROWS * HEADS;    // 256,000
    float* abuf   = wsf + off; off += (size_t)GG * EP * HEADS; // 2,304,000
    float* gib    = wsf + off; off += GOSZ;                    // 12,288
    float* hTb    = wsf + off; off += 256;
    int* ib = (int*)(wsf + off);
    int* src_e   = ib;           ib += EP;
    int* dst_e   = ib;           ib += EP;
    int* rowptr  = ib;           ib += NNODE + 1;
    int* csr_src = ib;           ib += EP;
    int* deg     = ib;           ib += NNODE;
    int* fill    = ib;           ib += NNODE;

    // gi partials alias hbuf (dead after last k_agg): 500*12288 + 10*12288 floats << 16.38M
    float* gip  = hbuf;
    float* gip2 = hbuf + (size_t)KSPLIT * GOSZ;

    k_build_edges<<<(EP + 255) / 256, 256, 0, stream>>>(eidx, src_e, dst_e, deg, fill);
    k_csr_count<<<(EP + 255) / 256, 256, 0, stream>>>(dst_e, deg);
    k_csr_scan<<<1, 256, 0, stream>>>(deg, rowptr);
    k_csr_fill<<<(EP + 255) / 256, 256, 0, stream>>>(src_e, dst_e, rowptr, fill, csr_src);

    k_input_fc<<<ROWS * 16 / 256, 256, 0, stream>>>(x_seq, (const float4*)W_in, (const float4*)b_in,
                                                    (float4*)x0);

    const float* xcur = x0;
    float* xnext = x1;
    for (int l = 0; l < NL; l++) {
        k_gat_h<<<dim3(ROWS / 64, HEADS), 256, 0, stream>>>(
            (const float4*)xcur, (const float4*)(Wg + (size_t)l * HID * HCOL),
            a_src + (size_t)l * HEADS * HID, a_dst + (size_t)l * HEADS * HID, hbuf, lsb, ldb);
        k_alpha<<<(GG * NNODE + 255) / 256, 256, 0, stream>>>(
            (const float4*)lsb, (const float4*)ldb, rowptr, csr_src, (float4*)abuf);
        k_agg<<<dim3(NNODE, GG / 4), 256, 0, stream>>>(
            (const float4*)hbuf, abuf, rowptr, csr_src,
            (const float4*)(bg + (size_t)l * HID), (float4*)xnext);
        const float* tmp = xcur; xcur = xnext; xnext = (float*)tmp;
    }

    k_gi_gemm<<<KSPLIT, 256, 0, stream>>>(xcur, W_ih, gip);
    k_gi_reduce1<<<dim3(GOSZ / 256, 10), 256, 0, stream>>>(gip, gip2);
    k_gi_reduce2<<<GOSZ / 256, 256, 0, stream>>>(gip2, b_ih, gib);
    k_gru<<<1, 256, 0, stream>>>(gib, W_hh, b_hh, hTb);
    k_final<<<(NB * NNODE + 255) / 256, 256, 0, stream>>>(hTb, W_fc, b_fc, out);
}

// Round 6
// 876.342 us; speedup vs baseline: 1.1792x; 1.0400x over previous
//
#include <hip/hip_runtime.h>
#include <math.h>

#define NB 4
#define TT 16
#define NNODE 1000
#define FIN 8
#define EE 8000
#define EP 9000          // E + N self loops
#define HID 64
#define HEADS 4
#define NL 5
#define GG (NB*TT)       // 64 graphs
#define ROWS (GG*NNODE)  // 64000
#define HCOL (HEADS*HID) // 256
#define KGI (NNODE*HID)  // 64000
#define GOUT 192         // 3*HID
#define GIK 128          // K-slice per gi-gemm block
#define KSPLIT (KGI/GIK) // 500 partial slabs
#define GOSZ (GG*GOUT)   // 12288

// ---------------- edge prep ----------------
__global__ void k_build_edges(const int* __restrict__ eidx, int* __restrict__ src_e,
                              int* __restrict__ dst_e, int* __restrict__ deg, int* __restrict__ fill) {
    int i = blockIdx.x * blockDim.x + threadIdx.x;
    if (i < EP) {
        int s, d;
        if (i < EE) { s = eidx[i]; d = eidx[EE + i]; }
        else { s = i - EE; d = i - EE; }
        src_e[i] = s; dst_e[i] = d;
    }
    if (i < NNODE) { deg[i] = 0; fill[i] = 0; }
}

__global__ void k_csr_count(const int* __restrict__ dst_e, int* __restrict__ deg) {
    int i = blockIdx.x * blockDim.x + threadIdx.x;
    if (i < EP) atomicAdd(&deg[dst_e[i]], 1);
}

// parallel inclusive scan over 1024 (padded) in LDS
__global__ __launch_bounds__(256) void k_csr_scan(const int* __restrict__ deg, int* __restrict__ rowptr) {
    __shared__ int s[1024];
    int tid = threadIdx.x;
    for (int i = tid; i < 1024; i += 256) s[i] = (i < NNODE) ? deg[i] : 0;
    __syncthreads();
    for (int off = 1; off < 1024; off <<= 1) {
        int t[4];
        #pragma unroll
        for (int q = 0; q < 4; q++) { int i = tid + 256 * q; t[q] = (i >= off) ? s[i - off] : 0; }
        __syncthreads();
        #pragma unroll
        for (int q = 0; q < 4; q++) { int i = tid + 256 * q; s[i] += t[q]; }
        __syncthreads();
    }
    for (int i = tid; i < NNODE; i += 256) rowptr[i + 1] = s[i];
    if (tid == 0) rowptr[0] = 0;
}

__global__ void k_csr_fill(const int* __restrict__ src_e, const int* __restrict__ dst_e,
                           const int* __restrict__ rowptr, int* __restrict__ fill,
                           int* __restrict__ csr_src) {
    int i = blockIdx.x * blockDim.x + threadIdx.x;
    if (i < EP) {
        int d = dst_e[i];
        int pos = atomicAdd(&fill[d], 1);
        csr_src[rowptr[d] + pos] = src_e[i];
    }
}

// ---------------- input projection (float4 over columns) ----------------
__global__ void k_input_fc(const float* __restrict__ xseq, const float4* __restrict__ Win4,
                           const float4* __restrict__ b_in4, float4* __restrict__ x0) {
    int idx = blockIdx.x * 256 + threadIdx.x;   // ROWS*16 threads
    int r = idx >> 4, c4 = idx & 15;
    float4 acc = b_in4[c4];
    #pragma unroll
    for (int k = 0; k < FIN; k++) {
        float xv = xseq[r * FIN + k];
        float4 w = Win4[k * 16 + c4];
        acc.x += xv * w.x; acc.y += xv * w.y; acc.z += xv * w.z; acc.w += xv * w.w;
    }
    x0[idx] = acc;
}

// ---------------- GAT: h = x @ W, plus ls/ld attention dots ----------------
__global__ __launch_bounds__(256) void k_gat_h(const float4* __restrict__ x4, const float4* __restrict__ W4,
                                               const float* __restrict__ asrc, const float* __restrict__ adst,
                                               float* __restrict__ h, float* __restrict__ ls, float* __restrict__ ld) {
    __shared__ float xs[64 * 68];                 // [k][row] transposed, pitch 68
    __shared__ __align__(16) float ws[64 * 64];   // [k][c]
    int r0 = blockIdx.x * 64;
    int head = blockIdx.y;
    int c0 = head * 64;
    int tid = threadIdx.x;
    // lane-major staging: within a wave kq is constant, row = lane -> conflict-free writes
    int a = tid & 63;
    #pragma unroll
    for (int it = 0; it < 4; it++) {
        int kq = (tid >> 6) + 4 * it;             // 0..15
        float4 v = x4[(size_t)(r0 + a) * 16 + kq];
        int k = kq * 4;
        xs[(k + 0) * 68 + a] = v.x;
        xs[(k + 1) * 68 + a] = v.y;
        xs[(k + 2) * 68 + a] = v.z;
        xs[(k + 3) * 68 + a] = v.w;
    }
    for (int idx = tid; idx < 1024; idx += 256) {
        int k = idx >> 4, j = idx & 15;
        *reinterpret_cast<float4*>(&ws[k * 64 + j * 4]) = W4[(size_t)k * 64 + head * 16 + j];
    }
    __syncthreads();
    int tx = tid & 15, ty = tid >> 4;
    float acc[4][4] = {};
    for (int k = 0; k < 64; k++) {
        float4 xv = *reinterpret_cast<const float4*>(&xs[k * 68 + ty * 4]);
        float4 w4 = *reinterpret_cast<const float4*>(&ws[k * 64 + tx * 4]);
        acc[0][0] += xv.x * w4.x; acc[0][1] += xv.x * w4.y; acc[0][2] += xv.x * w4.z; acc[0][3] += xv.x * w4.w;
        acc[1][0] += xv.y * w4.x; acc[1][1] += xv.y * w4.y; acc[1][2] += xv.y * w4.z; acc[1][3] += xv.y * w4.w;
        acc[2][0] += xv.z * w4.x; acc[2][1] += xv.z * w4.y; acc[2][2] += xv.z * w4.z; acc[2][3] += xv.z * w4.w;
        acc[3][0] += xv.w * w4.x; acc[3][1] += xv.w * w4.y; acc[3][2] += xv.w * w4.z; acc[3][3] += xv.w * w4.w;
    }
    #pragma unroll
    for (int i = 0; i < 4; i++) {
        float4 v = make_float4(acc[i][0], acc[i][1], acc[i][2], acc[i][3]);
        *reinterpret_cast<float4*>(&h[(size_t)(r0 + ty * 4 + i) * HCOL + c0 + tx * 4]) = v;
    }
    float a0 = asrc[c0 + tx * 4 + 0], a1 = asrc[c0 + tx * 4 + 1];
    float a2 = asrc[c0 + tx * 4 + 2], a3 = asrc[c0 + tx * 4 + 3];
    float d0 = adst[c0 + tx * 4 + 0], d1 = adst[c0 + tx * 4 + 1];
    float d2 = adst[c0 + tx * 4 + 2], d3 = adst[c0 + tx * 4 + 3];
    #pragma unroll
    for (int i = 0; i < 4; i++) {
        float ps = acc[i][0] * a0 + acc[i][1] * a1 + acc[i][2] * a2 + acc[i][3] * a3;
        float pd = acc[i][0] * d0 + acc[i][1] * d1 + acc[i][2] * d2 + acc[i][3] * d3;
        #pragma unroll
        for (int m = 1; m < 16; m <<= 1) {
            ps += __shfl_xor(ps, m, 64);
            pd += __shfl_xor(pd, m, 64);
        }
        if (tx == 0) {
            ls[(size_t)(r0 + ty * 4 + i) * HEADS + head] = ps;
            ld[(size_t)(r0 + ty * 4 + i) * HEADS + head] = pd;
        }
    }
}

// ---------------- fused logits + softmax + alpha, per (g,n), 4 heads as float4 ----------------
__global__ __launch_bounds__(256) void k_alpha(const float4* __restrict__ ls4, const float4* __restrict__ ld4,
                                               const int* __restrict__ rowptr, const int* __restrict__ csr_src,
                                               float4* __restrict__ abuf) {
    int idx = blockIdx.x * 256 + threadIdx.x;     // GG*NNODE
    if (idx >= GG * NNODE) return;
    int g = idx / NNODE, n = idx - g * NNODE;
    int rs = rowptr[n], re = rowptr[n + 1];
    int dg = re - rs;
    float4 ldv = ld4[(size_t)g * NNODE + n];
    const float4* lsg = ls4 + (size_t)g * NNODE;
    float4* out = abuf + (size_t)g * EP;
    if (dg <= 16) {
        int sv[16];
        float4 v[16];
        #pragma unroll
        for (int u = 0; u < 16; u++) sv[u] = (u < dg) ? csr_src[rs + u] : 0;
        #pragma unroll
        for (int u = 0; u < 16; u++) {
            if (u < dg) {
                float4 t = lsg[sv[u]];
                t.x += ldv.x; t.y += ldv.y; t.z += ldv.z; t.w += ldv.w;
                t.x = t.x >= 0.f ? t.x : 0.2f * t.x;
                t.y = t.y >= 0.f ? t.y : 0.2f * t.y;
                t.z = t.z >= 0.f ? t.z : 0.2f * t.z;
                t.w = t.w >= 0.f ? t.w : 0.2f * t.w;
                v[u] = t;
            }
        }
        float4 m = make_float4(-1e30f, -1e30f, -1e30f, -1e30f);
        #pragma unroll
        for (int u = 0; u < 16; u++) {
            if (u < dg) {
                m.x = fmaxf(m.x, v[u].x); m.y = fmaxf(m.y, v[u].y);
                m.z = fmaxf(m.z, v[u].z); m.w = fmaxf(m.w, v[u].w);
            }
        }
        float4 den = make_float4(0.f, 0.f, 0.f, 0.f);
        #pragma unroll
        for (int u = 0; u < 16; u++) {
            if (u < dg) {
                v[u].x = expf(v[u].x - m.x); den.x += v[u].x;
                v[u].y = expf(v[u].y - m.y); den.y += v[u].y;
                v[u].z = expf(v[u].z - m.z); den.z += v[u].z;
                v[u].w = expf(v[u].w - m.w); den.w += v[u].w;
            }
        }
        float4 inv = make_float4(1.f / (den.x + 1e-16f), 1.f / (den.y + 1e-16f),
                                 1.f / (den.z + 1e-16f), 1.f / (den.w + 1e-16f));
        #pragma unroll
        for (int u = 0; u < 16; u++) {
            if (u < dg) {
                float4 t = make_float4(v[u].x * inv.x, v[u].y * inv.y, v[u].z * inv.z, v[u].w * inv.w);
                out[rs + u] = t;
            }
        }
    } else {
        float4 m = make_float4(-1e30f, -1e30f, -1e30f, -1e30f);
        for (int j = rs; j < re; j++) {
            float4 t = lsg[csr_src[j]];
            t.x += ldv.x; t.y += ldv.y; t.z += ldv.z; t.w += ldv.w;
            t.x = t.x >= 0.f ? t.x : 0.2f * t.x;
            t.y = t.y >= 0.f ? t.y : 0.2f * t.y;
            t.z = t.z >= 0.f ? t.z : 0.2f * t.z;
            t.w = t.w >= 0.f ? t.w : 0.2f * t.w;
            out[j] = t;
            m.x = fmaxf(m.x, t.x); m.y = fmaxf(m.y, t.y);
            m.z = fmaxf(m.z, t.z); m.w = fmaxf(m.w, t.w);
        }
        float4 den = make_float4(0.f, 0.f, 0.f, 0.f);
        for (int j = rs; j < re; j++) {
            float4 t = out[j];
            t.x = expf(t.x - m.x); den.x += t.x;
            t.y = expf(t.y - m.y); den.y += t.y;
            t.z = expf(t.z - m.z); den.z += t.z;
            t.w = expf(t.w - m.w); den.w += t.w;
            out[j] = t;
        }
        float4 inv = make_float4(1.f / (den.x + 1e-16f), 1.f / (den.y + 1e-16f),
                                 1.f / (den.z + 1e-16f), 1.f / (den.w + 1e-16f));
        for (int j = rs; j < re; j++) {
            float4 t = out[j];
            t.x *= inv.x; t.y *= inv.y; t.z *= inv.z; t.w *= inv.w;
            out[j] = t;
        }
    }
}

// ---------------- GAT aggregate: one wave per (g,n), XCD-swizzled so one graph stays on one XCD ----------------
__global__ __launch_bounds__(256) void k_agg(const float4* __restrict__ h4, const float* __restrict__ alpha,
                                             const int* __restrict__ rowptr, const int* __restrict__ csr_src,
                                             const float4* __restrict__ bg4, float4* __restrict__ xout4) {
    int b = blockIdx.x;              // 0..15999
    int xcd = b & 7, s = b >> 3;     // round-robin block->XCD heuristic
    int g = xcd + 8 * (s / 250);     // 8 graphs per XCD, processed sequentially
    int nb = s % 250;
    int tid = threadIdx.x;
    int wid = tid >> 6, lane = tid & 63;
    int n = nb * 4 + wid;            // 4 waves = 4 consecutive nodes of SAME graph
    int head = lane >> 4, c4 = lane & 15;
    int rs = rowptr[n], re = rowptr[n + 1];
    int dg = re - rs;
    const int* sp = csr_src + rs;
    const float* ag = alpha + ((size_t)g * EP + rs) * HEADS + head;
    const float4* hg = h4 + (size_t)g * NNODE * 64 + head * 16 + c4;
    float4 acc = make_float4(0.f, 0.f, 0.f, 0.f);
    for (int j0 = 0; j0 < dg; j0 += 16) {
        int cnt = dg - j0;
        int sv[16]; float av[16];
        #pragma unroll
        for (int u = 0; u < 16; u++) {
            bool ok = u < cnt;
            sv[u] = ok ? sp[j0 + u] : 0;
            av[u] = ok ? ag[(size_t)(j0 + u) * HEADS] : 0.f;
        }
        float4 hv[16];
        #pragma unroll
        for (int u = 0; u < 16; u++) hv[u] = hg[(size_t)sv[u] * 64];
        #pragma unroll
        for (int u = 0; u < 16; u++) {
            acc.x += av[u] * hv[u].x;
            acc.y += av[u] * hv[u].y;
            acc.z += av[u] * hv[u].z;
            acc.w += av[u] * hv[u].w;
        }
    }
    #pragma unroll
    for (int m = 16; m < 64; m <<= 1) {
        acc.x += __shfl_xor(acc.x, m, 64);
        acc.y += __shfl_xor(acc.y, m, 64);
        acc.z += __shfl_xor(acc.z, m, 64);
        acc.w += __shfl_xor(acc.w, m, 64);
    }
    if (head == 0) {
        float4 bb = bg4[c4];
        acc.x = acc.x * 0.25f + bb.x;
        acc.y = acc.y * 0.25f + bb.y;
        acc.z = acc.z * 0.25f + bb.z;
        acc.w = acc.w * 0.25f + bb.w;
        acc.x = acc.x > 0.f ? acc.x : expm1f(acc.x);
        acc.y = acc.y > 0.f ? acc.y : expm1f(acc.y);
        acc.z = acc.z > 0.f ? acc.z : expm1f(acc.z);
        acc.w = acc.w > 0.f ? acc.w : expm1f(acc.w);
        xout4[((size_t)g * NNODE + n) * 16 + c4] = acc;
    }
}

// ---------------- GRU input GEMM: 500 K-slices, full 64x192 tile/block, no atomics ----------------
__global__ __launch_bounds__(256) void k_gi_gemm(const float* __restrict__ x, const float* __restrict__ W_ih,
                                                 float* __restrict__ gip) {
    __shared__ float xs[32 * 68];    // [kk][row], pitch 68
    __shared__ float ws[32 * 196];   // [kk][col 0..191], pitch 196
    int k0 = blockIdx.x * GIK;
    int tid = threadIdx.x;
    int lane = tid & 63;
    int wv = tid >> 6;               // wave id 0..3 (kq base, uniform per wave)
    int tx = tid & 15, ty = tid >> 4;
    float4 accs[4][3];
    #pragma unroll
    for (int i = 0; i < 4; i++)
        #pragma unroll
        for (int j = 0; j < 3; j++) accs[i][j] = make_float4(0.f, 0.f, 0.f, 0.f);

    for (int kt = 0; kt < GIK / 32; kt++) {
        int kb = k0 + kt * 32;
        #pragma unroll
        for (int it = 0; it < 2; it++) {
            int kq = wv + 4 * it;    // 0..7, uniform per wave
            float4 v = *reinterpret_cast<const float4*>(&x[(size_t)lane * KGI + kb + kq * 4]);
            int k = kq * 4;
            xs[(k + 0) * 68 + lane] = v.x;
            xs[(k + 1) * 68 + lane] = v.y;
            xs[(k + 2) * 68 + lane] = v.z;
            xs[(k + 3) * 68 + lane] = v.w;
        }
        #pragma unroll
        for (int cg = 0; cg < 3; cg++) {
            #pragma unroll
            for (int it = 0; it < 2; it++) {
                int kq = wv + 4 * it;
                int c = cg * 64 + lane;
                float4 v = *reinterpret_cast<const float4*>(&W_ih[(size_t)c * KGI + kb + kq * 4]);
                int k = kq * 4;
                ws[(k + 0) * 196 + c] = v.x;
                ws[(k + 1) * 196 + c] = v.y;
                ws[(k + 2) * 196 + c] = v.z;
                ws[(k + 3) * 196 + c] = v.w;
            }
        }
        __syncthreads();
        for (int kk = 0; kk < 32; kk++) {
            float4 xv = *reinterpret_cast<const float4*>(&xs[kk * 68 + ty * 4]);
            float4 w0 = *reinterpret_cast<const float4*>(&ws[kk * 196 + tx * 4]);
            float4 w1 = *reinterpret_cast<const float4*>(&ws[kk * 196 + 64 + tx * 4]);
            float4 w2 = *reinterpret_cast<const float4*>(&ws[kk * 196 + 128 + tx * 4]);
            #pragma unroll
            for (int i = 0; i < 4; i++) {
                float xi = (i == 0) ? xv.x : (i == 1) ? xv.y : (i == 2) ? xv.z : xv.w;
                accs[i][0].x += xi * w0.x; accs[i][0].y += xi * w0.y; accs[i][0].z += xi * w0.z; accs[i][0].w += xi * w0.w;
                accs[i][1].x += xi * w1.x; accs[i][1].y += xi * w1.y; accs[i][1].z += xi * w1.z; accs[i][1].w += xi * w1.w;
                accs[i][2].x += xi * w2.x; accs[i][2].y += xi * w2.y; accs[i][2].z += xi * w2.z; accs[i][2].w += xi * w2.w;
            }
        }
        __syncthreads();
    }
    float* out = gip + (size_t)blockIdx.x * GOSZ;
    #pragma unroll
    for (int i = 0; i < 4; i++)
        #pragma unroll
        for (int j = 0; j < 3; j++)
            *reinterpret_cast<float4*>(&out[(ty * 4 + i) * GOUT + j * 64 + tx * 4]) = accs[i][j];
}

__global__ void k_gi_reduce1(const float* __restrict__ gip, float* __restrict__ gip2) {
    int idx = blockIdx.x * 256 + threadIdx.x;     // 0..GOSZ-1
    const float* p = gip + (size_t)blockIdx.y * 50 * GOSZ + idx;
    float a = 0.f;
    #pragma unroll 5
    for (int s = 0; s < 50; s++) a += p[(size_t)s * GOSZ];
    gip2[blockIdx.y * GOSZ + idx] = a;
}

__global__ void k_gi_reduce2(const float* __restrict__ gip2, const float* __restrict__ b_ih,
                             float* __restrict__ gi) {
    int idx = blockIdx.x * 256 + threadIdx.x;
    float a = b_ih[idx % GOUT];
    #pragma unroll
    for (int y = 0; y < 10; y++) a += gip2[(size_t)y * GOSZ + idx];
    gi[idx] = a;
}

// ---------------- GRU scan (single block) ----------------
__global__ __launch_bounds__(256) void k_gru(const float* __restrict__ gi, const float* __restrict__ W_hh,
                                             const float* __restrict__ b_hh, float* __restrict__ hT) {
    __shared__ float Wt[64 * 192];   // [c][j] transposed
    __shared__ float hs[4][64];
    __shared__ float gh[4][192];
    int tid = threadIdx.x;
    for (int idx = tid; idx < 192 * 64; idx += 256) {
        int j = idx >> 6, c = idx & 63;
        Wt[c * 192 + j] = W_hh[idx];
    }
    int b_ = tid >> 6, c_ = tid & 63;
    hs[b_][c_] = 0.f;
    __syncthreads();
    for (int t = 0; t < TT; t++) {
        #pragma unroll
        for (int q = 0; q < 3; q++) {
            int p = tid + 256 * q;
            int bb = p / GOUT, j = p % GOUT;
            float a = b_hh[j];
            for (int c = 0; c < 64; c++) a += hs[bb][c] * Wt[c * 192 + j];
            gh[bb][j] = a;
        }
        __syncthreads();
        int row = (b_ * TT + t) * GOUT;
        float ir = gi[row + c_], iz = gi[row + 64 + c_], in_ = gi[row + 128 + c_];
        float r = 1.f / (1.f + expf(-(ir + gh[b_][c_])));
        float z = 1.f / (1.f + expf(-(iz + gh[b_][64 + c_])));
        float nv = tanhf(in_ + r * gh[b_][128 + c_]);
        float hn = (1.f - z) * nv + z * hs[b_][c_];
        hs[b_][c_] = hn;
        __syncthreads();
    }
    hT[tid] = hs[b_][c_];
}

// ---------------- final FC ----------------
__global__ void k_final(const float* __restrict__ hT, const float* __restrict__ W_fc,
                        const float* __restrict__ b_fc, float* __restrict__ out) {
    int idx = blockIdx.x * 256 + threadIdx.x;
    if (idx >= NB * NNODE) return;
    int b = idx / NNODE, n = idx % NNODE;
    float acc = b_fc[n];
    #pragma unroll
    for (int c = 0; c < HID; c++) acc += hT[b * HID + c] * W_fc[c * NNODE + n];
    out[idx] = acc;
}

extern "C" void kernel_launch(void* const* d_in, const int* in_sizes, int n_in,
                              void* d_out, int out_size, void* d_ws, size_t ws_size,
                              hipStream_t stream) {
    const float* x_seq  = (const float*)d_in[0];
    const int*   eidx   = (const int*)  d_in[1];
    // d_in[2] edge_weight: unused by GATConv
    const float* W_in   = (const float*)d_in[3];
    const float* b_in   = (const float*)d_in[4];
    const float* Wg     = (const float*)d_in[5];
    const float* a_src  = (const float*)d_in[6];
    const float* a_dst  = (const float*)d_in[7];
    const float* bg     = (const float*)d_in[8];
    const float* W_ih   = (const float*)d_in[9];
    const float* W_hh   = (const float*)d_in[10];
    const float* b_ih   = (const float*)d_in[11];
    const float* b_hh   = (const float*)d_in[12];
    const float* W_fc   = (const float*)d_in[13];
    const float* b_fc   = (const float*)d_in[14];
    float* out = (float*)d_out;

    float* wsf = (float*)d_ws;
    size_t off = 0;
    float* x0     = wsf + off; off += (size_t)ROWS * HID;      // 4,096,000
    float* x1     = wsf + off; off += (size_t)ROWS * HID;      // 4,096,000
    float* hbuf   = wsf + off; off += (size_t)ROWS * HCOL;     // 16,384,000
    float* lsb    = wsf + off; off += (size_t)ROWS * HEADS;    // 256,000
    float* ldb    = wsf + off; off += (size_t)ROWS * HEADS;    // 256,000
    float* abuf   = wsf + off; off += (size_t)GG * EP * HEADS; // 2,304,000
    float* gib    = wsf + off; off += GOSZ;                    // 12,288
    float* hTb    = wsf + off; off += 256;
    int* ib = (int*)(wsf + off);
    int* src_e   = ib;           ib += EP;
    int* dst_e   = ib;           ib += EP;
    int* rowptr  = ib;           ib += NNODE + 1;
    int* csr_src = ib;           ib += EP;
    int* deg     = ib;           ib += NNODE;
    int* fill    = ib;           ib += NNODE;

    // gi partials alias hbuf (dead after last k_agg): 500*12288 + 10*12288 floats << 16.38M
    float* gip  = hbuf;
    float* gip2 = hbuf + (size_t)KSPLIT * GOSZ;

    k_build_edges<<<(EP + 255) / 256, 256, 0, stream>>>(eidx, src_e, dst_e, deg, fill);
    k_csr_count<<<(EP + 255) / 256, 256, 0, stream>>>(dst_e, deg);
    k_csr_scan<<<1, 256, 0, stream>>>(deg, rowptr);
    k_csr_fill<<<(EP + 255) / 256, 256, 0, stream>>>(src_e, dst_e, rowptr, fill, csr_src);

    k_input_fc<<<ROWS * 16 / 256, 256, 0, stream>>>(x_seq, (const float4*)W_in, (const float4*)b_in,
                                                    (float4*)x0);

    const float* xcur = x0;
    float* xnext = x1;
    for (int l = 0; l < NL; l++) {
        k_gat_h<<<dim3(ROWS / 64, HEADS), 256, 0, stream>>>(
            (const float4*)xcur, (const float4*)(Wg + (size_t)l * HID * HCOL),
            a_src + (size_t)l * HEADS * HID, a_dst + (size_t)l * HEADS * HID, hbuf, lsb, ldb);
        k_alpha<<<(GG * NNODE + 255) / 256, 256, 0, stream>>>(
            (const float4*)lsb, (const float4*)ldb, rowptr, csr_src, (float4*)abuf);
        k_agg<<<ROWS / 4, 256, 0, stream>>>(
            (const float4*)hbuf, abuf, rowptr, csr_src,
            (const float4*)(bg + (size_t)l * HID), (float4*)xnext);
        const float* tmp = xcur; xcur = xnext; xnext = (float*)tmp;
    }

    k_gi_gemm<<<KSPLIT, 256, 0, stream>>>(xcur, W_ih, gip);
    k_gi_reduce1<<<dim3(GOSZ / 256, 10), 256, 0, stream>>>(gip, gip2);
    k_gi_reduce2<<<GOSZ / 256, 256, 0, stream>>>(gip2, b_ih, gib);
    k_gru<<<1, 256, 0, stream>>>(gib, W_hh, b_hh, hTb);
    k_final<<<(NB * NNODE + 255) / 256, 256, 0, stream>>>(hTb, W_fc, b_fc, out);
}

// Round 7
// 803.646 us; speedup vs baseline: 1.2859x; 1.0905x over previous
//
#include <hip/hip_runtime.h>
#include <math.h>

#define NB 4
#define TT 16
#define NNODE 1000
#define FIN 8
#define EE 8000
#define EP 9000          // E + N self loops
#define EPAD 24064       // max padded edges: EP + NNODE*15 = 24000, rounded up
#define HID 64
#define HEADS 4
#define NL 5
#define GG (NB*TT)       // 64 graphs
#define ROWS (GG*NNODE)  // 64000
#define HCOL (HEADS*HID) // 256
#define KGI (NNODE*HID)  // 64000
#define GOUT 192         // 3*HID
#define GIK 128          // K-slice per gi-gemm block
#define KSPLIT (KGI/GIK) // 500 partial slabs
#define GOSZ (GG*GOUT)   // 12288

// ---------------- edge prep ----------------
__global__ void k_build_edges(const int* __restrict__ eidx, int* __restrict__ src_e,
                              int* __restrict__ dst_e, int* __restrict__ deg, int* __restrict__ fill) {
    int i = blockIdx.x * blockDim.x + threadIdx.x;
    if (i < EP) {
        int s, d;
        if (i < EE) { s = eidx[i]; d = eidx[EE + i]; }
        else { s = i - EE; d = i - EE; }
        src_e[i] = s; dst_e[i] = d;
    }
    if (i < NNODE) { deg[i] = 0; fill[i] = 0; }
}

__global__ void k_csr_count(const int* __restrict__ dst_e, int* __restrict__ deg) {
    int i = blockIdx.x * blockDim.x + threadIdx.x;
    if (i < EP) atomicAdd(&deg[dst_e[i]], 1);
}

// parallel inclusive scan of PADDED degrees (pad to multiple of 16)
__global__ __launch_bounds__(256) void k_csr_scan(const int* __restrict__ deg, int* __restrict__ rowptr_p) {
    __shared__ int s[1024];
    int tid = threadIdx.x;
    for (int i = tid; i < 1024; i += 256) s[i] = (i < NNODE) ? ((deg[i] + 15) & ~15) : 0;
    __syncthreads();
    for (int off = 1; off < 1024; off <<= 1) {
        int t[4];
        #pragma unroll
        for (int q = 0; q < 4; q++) { int i = tid + 256 * q; t[q] = (i >= off) ? s[i - off] : 0; }
        __syncthreads();
        #pragma unroll
        for (int q = 0; q < 4; q++) { int i = tid + 256 * q; s[i] += t[q]; }
        __syncthreads();
    }
    for (int i = tid; i < NNODE; i += 256) rowptr_p[i + 1] = s[i];
    if (tid == 0) rowptr_p[0] = 0;
}

__global__ void k_csr_fill(const int* __restrict__ src_e, const int* __restrict__ dst_e,
                           const int* __restrict__ rowptr_p, int* __restrict__ fill,
                           int* __restrict__ csr_src) {
    int i = blockIdx.x * blockDim.x + threadIdx.x;
    if (i < EP) {
        int d = dst_e[i];
        int pos = atomicAdd(&fill[d], 1);
        csr_src[rowptr_p[d] + pos] = src_e[i];
    }
}

// fill pad slots with dummy self-edges (alpha will assign them weight 0)
__global__ void k_pad_fill(const int* __restrict__ rowptr_p, const int* __restrict__ deg,
                           int* __restrict__ csr_src) {
    int n = blockIdx.x * blockDim.x + threadIdx.x;
    if (n >= NNODE) return;
    int rs = rowptr_p[n], re = rowptr_p[n + 1];
    for (int j = rs + deg[n]; j < re; j++) csr_src[j] = n;
}

// ---------------- input projection (float4 over columns) ----------------
__global__ void k_input_fc(const float* __restrict__ xseq, const float4* __restrict__ Win4,
                           const float4* __restrict__ b_in4, float4* __restrict__ x0) {
    int idx = blockIdx.x * 256 + threadIdx.x;   // ROWS*16 threads
    int r = idx >> 4, c4 = idx & 15;
    float4 acc = b_in4[c4];
    #pragma unroll
    for (int k = 0; k < FIN; k++) {
        float xv = xseq[r * FIN + k];
        float4 w = Win4[k * 16 + c4];
        acc.x += xv * w.x; acc.y += xv * w.y; acc.z += xv * w.z; acc.w += xv * w.w;
    }
    x0[idx] = acc;
}

// ---------------- GAT: h = x @ W, plus ls/ld attention dots ----------------
__global__ __launch_bounds__(256) void k_gat_h(const float4* __restrict__ x4, const float4* __restrict__ W4,
                                               const float* __restrict__ asrc, const float* __restrict__ adst,
                                               float* __restrict__ h, float* __restrict__ ls, float* __restrict__ ld) {
    __shared__ float xs[64 * 68];                 // [k][row] transposed, pitch 68
    __shared__ __align__(16) float ws[64 * 64];   // [k][c]
    int r0 = blockIdx.x * 64;
    int head = blockIdx.y;
    int c0 = head * 64;
    int tid = threadIdx.x;
    int a = tid & 63;
    #pragma unroll
    for (int it = 0; it < 4; it++) {
        int kq = (tid >> 6) + 4 * it;             // 0..15
        float4 v = x4[(size_t)(r0 + a) * 16 + kq];
        int k = kq * 4;
        xs[(k + 0) * 68 + a] = v.x;
        xs[(k + 1) * 68 + a] = v.y;
        xs[(k + 2) * 68 + a] = v.z;
        xs[(k + 3) * 68 + a] = v.w;
    }
    for (int idx = tid; idx < 1024; idx += 256) {
        int k = idx >> 4, j = idx & 15;
        *reinterpret_cast<float4*>(&ws[k * 64 + j * 4]) = W4[(size_t)k * 64 + head * 16 + j];
    }
    __syncthreads();
    int tx = tid & 15, ty = tid >> 4;
    float acc[4][4] = {};
    for (int k = 0; k < 64; k++) {
        float4 xv = *reinterpret_cast<const float4*>(&xs[k * 68 + ty * 4]);
        float4 w4 = *reinterpret_cast<const float4*>(&ws[k * 64 + tx * 4]);
        acc[0][0] += xv.x * w4.x; acc[0][1] += xv.x * w4.y; acc[0][2] += xv.x * w4.z; acc[0][3] += xv.x * w4.w;
        acc[1][0] += xv.y * w4.x; acc[1][1] += xv.y * w4.y; acc[1][2] += xv.y * w4.z; acc[1][3] += xv.y * w4.w;
        acc[2][0] += xv.z * w4.x; acc[2][1] += xv.z * w4.y; acc[2][2] += xv.z * w4.z; acc[2][3] += xv.z * w4.w;
        acc[3][0] += xv.w * w4.x; acc[3][1] += xv.w * w4.y; acc[3][2] += xv.w * w4.z; acc[3][3] += xv.w * w4.w;
    }
    #pragma unroll
    for (int i = 0; i < 4; i++) {
        float4 v = make_float4(acc[i][0], acc[i][1], acc[i][2], acc[i][3]);
        *reinterpret_cast<float4*>(&h[(size_t)(r0 + ty * 4 + i) * HCOL + c0 + tx * 4]) = v;
    }
    float a0 = asrc[c0 + tx * 4 + 0], a1 = asrc[c0 + tx * 4 + 1];
    float a2 = asrc[c0 + tx * 4 + 2], a3 = asrc[c0 + tx * 4 + 3];
    float d0 = adst[c0 + tx * 4 + 0], d1 = adst[c0 + tx * 4 + 1];
    float d2 = adst[c0 + tx * 4 + 2], d3 = adst[c0 + tx * 4 + 3];
    #pragma unroll
    for (int i = 0; i < 4; i++) {
        float ps = acc[i][0] * a0 + acc[i][1] * a1 + acc[i][2] * a2 + acc[i][3] * a3;
        float pd = acc[i][0] * d0 + acc[i][1] * d1 + acc[i][2] * d2 + acc[i][3] * d3;
        #pragma unroll
        for (int m = 1; m < 16; m <<= 1) {
            ps += __shfl_xor(ps, m, 64);
            pd += __shfl_xor(pd, m, 64);
        }
        if (tx == 0) {
            ls[(size_t)(r0 + ty * 4 + i) * HEADS + head] = ps;
            ld[(size_t)(r0 + ty * 4 + i) * HEADS + head] = pd;
        }
    }
}

// ---------------- fused logits + softmax + alpha, per (g,n); writes PADDED alpha ----------------
__global__ __launch_bounds__(256) void k_alpha(const float4* __restrict__ ls4, const float4* __restrict__ ld4,
                                               const int* __restrict__ rowptr_p, const int* __restrict__ csr_src,
                                               const int* __restrict__ deg, float4* __restrict__ abuf) {
    int idx = blockIdx.x * 256 + threadIdx.x;     // GG*NNODE
    if (idx >= GG * NNODE) return;
    int g = idx / NNODE, n = idx - g * NNODE;
    int rs = rowptr_p[n], re = rowptr_p[n + 1];
    int dgp = re - rs;
    int dg = deg[n];
    float4 ldv = ld4[(size_t)g * NNODE + n];
    const float4* lsg = ls4 + (size_t)g * NNODE;
    float4* out = abuf + (size_t)g * EPAD;
    if (dgp == 16) {
        int sv[16];
        float4 v[16];
        #pragma unroll
        for (int u = 0; u < 16; u++) sv[u] = csr_src[rs + u];
        #pragma unroll
        for (int u = 0; u < 16; u++) {
            float4 t = lsg[sv[u]];
            t.x += ldv.x; t.y += ldv.y; t.z += ldv.z; t.w += ldv.w;
            t.x = fmaxf(t.x, 0.2f * t.x);
            t.y = fmaxf(t.y, 0.2f * t.y);
            t.z = fmaxf(t.z, 0.2f * t.z);
            t.w = fmaxf(t.w, 0.2f * t.w);
            v[u] = t;
        }
        float4 m = make_float4(-1e30f, -1e30f, -1e30f, -1e30f);
        #pragma unroll
        for (int u = 0; u < 16; u++) {
            if (u < dg) {
                m.x = fmaxf(m.x, v[u].x); m.y = fmaxf(m.y, v[u].y);
                m.z = fmaxf(m.z, v[u].z); m.w = fmaxf(m.w, v[u].w);
            }
        }
        float4 den = make_float4(0.f, 0.f, 0.f, 0.f);
        #pragma unroll
        for (int u = 0; u < 16; u++) {
            if (u < dg) {
                v[u].x = expf(v[u].x - m.x); den.x += v[u].x;
                v[u].y = expf(v[u].y - m.y); den.y += v[u].y;
                v[u].z = expf(v[u].z - m.z); den.z += v[u].z;
                v[u].w = expf(v[u].w - m.w); den.w += v[u].w;
            }
        }
        float4 inv = make_float4(1.f / (den.x + 1e-16f), 1.f / (den.y + 1e-16f),
                                 1.f / (den.z + 1e-16f), 1.f / (den.w + 1e-16f));
        #pragma unroll
        for (int u = 0; u < 16; u++) {
            float4 t = (u < dg)
                ? make_float4(v[u].x * inv.x, v[u].y * inv.y, v[u].z * inv.z, v[u].w * inv.w)
                : make_float4(0.f, 0.f, 0.f, 0.f);
            out[rs + u] = t;
        }
    } else {
        // general path (dgp >= 32)
        float4 m = make_float4(-1e30f, -1e30f, -1e30f, -1e30f);
        for (int j = rs; j < rs + dg; j++) {
            float4 t = lsg[csr_src[j]];
            t.x += ldv.x; t.y += ldv.y; t.z += ldv.z; t.w += ldv.w;
            t.x = fmaxf(t.x, 0.2f * t.x);
            t.y = fmaxf(t.y, 0.2f * t.y);
            t.z = fmaxf(t.z, 0.2f * t.z);
            t.w = fmaxf(t.w, 0.2f * t.w);
            out[j] = t;
            m.x = fmaxf(m.x, t.x); m.y = fmaxf(m.y, t.y);
            m.z = fmaxf(m.z, t.z); m.w = fmaxf(m.w, t.w);
        }
        float4 den = make_float4(0.f, 0.f, 0.f, 0.f);
        for (int j = rs; j < rs + dg; j++) {
            float4 t = out[j];
            t.x = expf(t.x - m.x); den.x += t.x;
            t.y = expf(t.y - m.y); den.y += t.y;
            t.z = expf(t.z - m.z); den.z += t.z;
            t.w = expf(t.w - m.w); den.w += t.w;
            out[j] = t;
        }
        float4 inv = make_float4(1.f / (den.x + 1e-16f), 1.f / (den.y + 1e-16f),
                                 1.f / (den.z + 1e-16f), 1.f / (den.w + 1e-16f));
        for (int j = rs; j < rs + dg; j++) {
            float4 t = out[j];
            t.x *= inv.x; t.y *= inv.y; t.z *= inv.z; t.w *= inv.w;
            out[j] = t;
        }
        for (int j = rs + dg; j < re; j++) out[j] = make_float4(0.f, 0.f, 0.f, 0.f);
    }
}

// ---------------- GAT aggregate: one wave per 4 nodes, unpredicated 16-chunks, XCD swizzle ----------------
__global__ __launch_bounds__(256) void k_agg(const float4* __restrict__ h4, const float* __restrict__ alpha,
                                             const int* __restrict__ rowptr_p, const int* __restrict__ csr_src,
                                             const float4* __restrict__ bg4, float4* __restrict__ xout4) {
    int b = blockIdx.x;              // 0..3999
    int xcd = b & 7, s = b >> 3;     // round-robin block->XCD heuristic
    int tid = threadIdx.x;
    int wid = tid >> 6, lane = tid & 63;
    int w = s * 4 + wid;             // 0..1999 per XCD
    int g = xcd + 8 * (w / 250);
    int n0 = (w % 250) * 4;
    int head = lane >> 4, c4 = lane & 15;
    const float* agg_base = alpha + (size_t)g * EPAD * HEADS + head;
    const float4* hg = h4 + (size_t)g * NNODE * 64 + lane;   // head*16+c4 == lane
    float4 bb = bg4[c4];

    #pragma unroll
    for (int nn = 0; nn < 4; nn++) {
        int n = n0 + nn;
        int rs = rowptr_p[n], re = rowptr_p[n + 1];
        float4 acc = make_float4(0.f, 0.f, 0.f, 0.f);
        for (int j0 = rs; j0 < re; j0 += 16) {
            int sv[16]; float av[16];
            const float* agc = agg_base + (size_t)j0 * HEADS;
            const int* sp = csr_src + j0;
            #pragma unroll
            for (int u = 0; u < 16; u++) {
                sv[u] = sp[u];
                av[u] = agc[u * HEADS];
            }
            float4 hv[16];
            #pragma unroll
            for (int u = 0; u < 16; u++) hv[u] = hg[(size_t)sv[u] * 64];
            #pragma unroll
            for (int u = 0; u < 16; u++) {
                acc.x += av[u] * hv[u].x;
                acc.y += av[u] * hv[u].y;
                acc.z += av[u] * hv[u].z;
                acc.w += av[u] * hv[u].w;
            }
        }
        #pragma unroll
        for (int m = 16; m < 64; m <<= 1) {
            acc.x += __shfl_xor(acc.x, m, 64);
            acc.y += __shfl_xor(acc.y, m, 64);
            acc.z += __shfl_xor(acc.z, m, 64);
            acc.w += __shfl_xor(acc.w, m, 64);
        }
        if (head == 0) {
            float4 r;
            r.x = acc.x * 0.25f + bb.x;
            r.y = acc.y * 0.25f + bb.y;
            r.z = acc.z * 0.25f + bb.z;
            r.w = acc.w * 0.25f + bb.w;
            r.x = r.x > 0.f ? r.x : expm1f(r.x);
            r.y = r.y > 0.f ? r.y : expm1f(r.y);
            r.z = r.z > 0.f ? r.z : expm1f(r.z);
            r.w = r.w > 0.f ? r.w : expm1f(r.w);
            xout4[((size_t)g * NNODE + n) * 16 + c4] = r;
        }
    }
}

// ---------------- GRU input GEMM: 500 K-slices, full 64x192 tile/block, no atomics ----------------
__global__ __launch_bounds__(256) void k_gi_gemm(const float* __restrict__ x, const float* __restrict__ W_ih,
                                                 float* __restrict__ gip) {
    __shared__ float xs[32 * 68];    // [kk][row], pitch 68
    __shared__ float ws[32 * 196];   // [kk][col 0..191], pitch 196
    int k0 = blockIdx.x * GIK;
    int tid = threadIdx.x;
    int lane = tid & 63;
    int wv = tid >> 6;
    int tx = tid & 15, ty = tid >> 4;
    float4 accs[4][3];
    #pragma unroll
    for (int i = 0; i < 4; i++)
        #pragma unroll
        for (int j = 0; j < 3; j++) accs[i][j] = make_float4(0.f, 0.f, 0.f, 0.f);

    for (int kt = 0; kt < GIK / 32; kt++) {
        int kb = k0 + kt * 32;
        #pragma unroll
        for (int it = 0; it < 2; it++) {
            int kq = wv + 4 * it;
            float4 v = *reinterpret_cast<const float4*>(&x[(size_t)lane * KGI + kb + kq * 4]);
            int k = kq * 4;
            xs[(k + 0) * 68 + lane] = v.x;
            xs[(k + 1) * 68 + lane] = v.y;
            xs[(k + 2) * 68 + lane] = v.z;
            xs[(k + 3) * 68 + lane] = v.w;
        }
        #pragma unroll
        for (int cg = 0; cg < 3; cg++) {
            #pragma unroll
            for (int it = 0; it < 2; it++) {
                int kq = wv + 4 * it;
                int c = cg * 64 + lane;
                float4 v = *reinterpret_cast<const float4*>(&W_ih[(size_t)c * KGI + kb + kq * 4]);
                int k = kq * 4;
                ws[(k + 0) * 196 + c] = v.x;
                ws[(k + 1) * 196 + c] = v.y;
                ws[(k + 2) * 196 + c] = v.z;
                ws[(k + 3) * 196 + c] = v.w;
            }
        }
        __syncthreads();
        for (int kk = 0; kk < 32; kk++) {
            float4 xv = *reinterpret_cast<const float4*>(&xs[kk * 68 + ty * 4]);
            float4 w0 = *reinterpret_cast<const float4*>(&ws[kk * 196 + tx * 4]);
            float4 w1 = *reinterpret_cast<const float4*>(&ws[kk * 196 + 64 + tx * 4]);
            float4 w2 = *reinterpret_cast<const float4*>(&ws[kk * 196 + 128 + tx * 4]);
            #pragma unroll
            for (int i = 0; i < 4; i++) {
                float xi = (i == 0) ? xv.x : (i == 1) ? xv.y : (i == 2) ? xv.z : xv.w;
                accs[i][0].x += xi * w0.x; accs[i][0].y += xi * w0.y; accs[i][0].z += xi * w0.z; accs[i][0].w += xi * w0.w;
                accs[i][1].x += xi * w1.x; accs[i][1].y += xi * w1.y; accs[i][1].z += xi * w1.z; accs[i][1].w += xi * w1.w;
                accs[i][2].x += xi * w2.x; accs[i][2].y += xi * w2.y; accs[i][2].z += xi * w2.z; accs[i][2].w += xi * w2.w;
            }
        }
        __syncthreads();
    }
    float* out = gip + (size_t)blockIdx.x * GOSZ;
    #pragma unroll
    for (int i = 0; i < 4; i++)
        #pragma unroll
        for (int j = 0; j < 3; j++)
            *reinterpret_cast<float4*>(&out[(ty * 4 + i) * GOUT + j * 64 + tx * 4]) = accs[i][j];
}

__global__ void k_gi_reduce1(const float* __restrict__ gip, float* __restrict__ gip2) {
    int idx = blockIdx.x * 256 + threadIdx.x;     // 0..GOSZ-1
    const float* p = gip + (size_t)blockIdx.y * 50 * GOSZ + idx;
    float a = 0.f;
    #pragma unroll 5
    for (int s = 0; s < 50; s++) a += p[(size_t)s * GOSZ];
    gip2[blockIdx.y * GOSZ + idx] = a;
}

__global__ void k_gi_reduce2(const float* __restrict__ gip2, const float* __restrict__ b_ih,
                             float* __restrict__ gi) {
    int idx = blockIdx.x * 256 + threadIdx.x;
    float a = b_ih[idx % GOUT];
    #pragma unroll
    for (int y = 0; y < 10; y++) a += gip2[(size_t)y * GOSZ + idx];
    gi[idx] = a;
}

// ---------------- GRU scan (single block) ----------------
__global__ __launch_bounds__(256) void k_gru(const float* __restrict__ gi, const float* __restrict__ W_hh,
                                             const float* __restrict__ b_hh, float* __restrict__ hT) {
    __shared__ float Wt[64 * 192];   // [c][j] transposed
    __shared__ float hs[4][64];
    __shared__ float gh[4][192];
    int tid = threadIdx.x;
    for (int idx = tid; idx < 192 * 64; idx += 256) {
        int j = idx >> 6, c = idx & 63;
        Wt[c * 192 + j] = W_hh[idx];
    }
    int b_ = tid >> 6, c_ = tid & 63;
    hs[b_][c_] = 0.f;
    __syncthreads();
    for (int t = 0; t < TT; t++) {
        #pragma unroll
        for (int q = 0; q < 3; q++) {
            int p = tid + 256 * q;
            int bb = p / GOUT, j = p % GOUT;
            float a = b_hh[j];
            for (int c = 0; c < 64; c++) a += hs[bb][c] * Wt[c * 192 + j];
            gh[bb][j] = a;
        }
        __syncthreads();
        int row = (b_ * TT + t) * GOUT;
        float ir = gi[row + c_], iz = gi[row + 64 + c_], in_ = gi[row + 128 + c_];
        float r = 1.f / (1.f + expf(-(ir + gh[b_][c_])));
        float z = 1.f / (1.f + expf(-(iz + gh[b_][64 + c_])));
        float nv = tanhf(in_ + r * gh[b_][128 + c_]);
        float hn = (1.f - z) * nv + z * hs[b_][c_];
        hs[b_][c_] = hn;
        __syncthreads();
    }
    hT[tid] = hs[b_][c_];
}

// ---------------- final FC ----------------
__global__ void k_final(const float* __restrict__ hT, const float* __restrict__ W_fc,
                        const float* __restrict__ b_fc, float* __restrict__ out) {
    int idx = blockIdx.x * 256 + threadIdx.x;
    if (idx >= NB * NNODE) return;
    int b = idx / NNODE, n = idx % NNODE;
    float acc = b_fc[n];
    #pragma unroll
    for (int c = 0; c < HID; c++) acc += hT[b * HID + c] * W_fc[c * NNODE + n];
    out[idx] = acc;
}

extern "C" void kernel_launch(void* const* d_in, const int* in_sizes, int n_in,
                              void* d_out, int out_size, void* d_ws, size_t ws_size,
                              hipStream_t stream) {
    const float* x_seq  = (const float*)d_in[0];
    const int*   eidx   = (const int*)  d_in[1];
    // d_in[2] edge_weight: unused by GATConv
    const float* W_in   = (const float*)d_in[3];
    const float* b_in   = (const float*)d_in[4];
    const float* Wg     = (const float*)d_in[5];
    const float* a_src  = (const float*)d_in[6];
    const float* a_dst  = (const float*)d_in[7];
    const float* bg     = (const float*)d_in[8];
    const float* W_ih   = (const float*)d_in[9];
    const float* W_hh   = (const float*)d_in[10];
    const float* b_ih   = (const float*)d_in[11];
    const float* b_hh   = (const float*)d_in[12];
    const float* W_fc   = (const float*)d_in[13];
    const float* b_fc   = (const float*)d_in[14];
    float* out = (float*)d_out;

    float* wsf = (float*)d_ws;
    size_t off = 0;
    float* x0     = wsf + off; off += (size_t)ROWS * HID;       // 4,096,000
    float* hbuf   = wsf + off; off += (size_t)ROWS * HCOL;      // 16,384,000
    float* lsb    = wsf + off; off += (size_t)ROWS * HEADS;     // 256,000
    float* ldb    = wsf + off; off += (size_t)ROWS * HEADS;     // 256,000
    float* abuf   = wsf + off; off += (size_t)GG * EPAD * HEADS;// 6,160,384
    float* gib    = wsf + off; off += GOSZ;                     // 12,288
    float* hTb    = wsf + off; off += 256;
    int* ib = (int*)(wsf + off);
    int* src_e    = ib;          ib += EP;
    int* dst_e    = ib;          ib += EP;
    int* rowptr_p = ib;          ib += NNODE + 1;
    int* csr_src  = ib;          ib += EPAD;
    int* deg      = ib;          ib += NNODE;
    int* fill     = ib;          ib += NNODE;

    // gi partials alias hbuf (dead after last k_agg): (500+10)*12288 floats << 16.38M
    float* gip  = hbuf;
    float* gip2 = hbuf + (size_t)KSPLIT * GOSZ;

    k_build_edges<<<(EP + 255) / 256, 256, 0, stream>>>(eidx, src_e, dst_e, deg, fill);
    k_csr_count<<<(EP + 255) / 256, 256, 0, stream>>>(dst_e, deg);
    k_csr_scan<<<1, 256, 0, stream>>>(deg, rowptr_p);
    k_csr_fill<<<(EP + 255) / 256, 256, 0, stream>>>(src_e, dst_e, rowptr_p, fill, csr_src);
    k_pad_fill<<<(NNODE + 255) / 256, 256, 0, stream>>>(rowptr_p, deg, csr_src);

    k_input_fc<<<ROWS * 16 / 256, 256, 0, stream>>>(x_seq, (const float4*)W_in, (const float4*)b_in,
                                                    (float4*)x0);

    for (int l = 0; l < NL; l++) {
        k_gat_h<<<dim3(ROWS / 64, HEADS), 256, 0, stream>>>(
            (const float4*)x0, (const float4*)(Wg + (size_t)l * HID * HCOL),
            a_src + (size_t)l * HEADS * HID, a_dst + (size_t)l * HEADS * HID, hbuf, lsb, ldb);
        k_alpha<<<(GG * NNODE + 255) / 256, 256, 0, stream>>>(
            (const float4*)lsb, (const float4*)ldb, rowptr_p, csr_src, deg, (float4*)abuf);
        k_agg<<<ROWS / 16, 256, 0, stream>>>(
            (const float4*)hbuf, abuf, rowptr_p, csr_src,
            (const float4*)(bg + (size_t)l * HID), (float4*)x0);
    }

    k_gi_gemm<<<KSPLIT, 256, 0, stream>>>(x0, W_ih, gip);
    k_gi_reduce1<<<dim3(GOSZ / 256, 10), 256, 0, stream>>>(gip, gip2);
    k_gi_reduce2<<<GOSZ / 256, 256, 0, stream>>>(gip2, b_ih, gib);
    k_gru<<<1, 256, 0, stream>>>(gib, W_hh, b_hh, hTb);
    k_final<<<(NB * NNODE + 255) / 256, 256, 0, stream>>>(hTb, W_fc, b_fc, out);
}